// Round 1
// baseline (330.889 us; speedup 1.0000x reference)
//
#include <hip/hip_runtime.h>
#include <hip/hip_bf16.h>
#include <math.h>

// (B,Cin,H,W)=(8,128,64,64), Cout=256, K=3, stride=1, pad=1, dil=1
#define B_    8
#define CIN   128
#define Hx    64
#define Wx    64
#define COUT  256
#define HW    4096
#define KTOT  1152      // CIN*9
#define NOFF  18
#define M_    32768     // B*HW
#define OFFSEG (B_ * NOFF * HW)   // 589824 floats per cin-segment partial
#define NCH   36        // K-chunks (chunk = 32 k)

typedef short bf16x8 __attribute__((ext_vector_type(8)));
typedef float f32x4  __attribute__((ext_vector_type(4)));

typedef __attribute__((address_space(1))) const unsigned int gu32;
typedef __attribute__((address_space(3))) unsigned int lu32;
static __device__ __forceinline__ void async_cp16(const short* g, short* l) {
  __builtin_amdgcn_global_load_lds((gu32*)g, (lu32*)l, 16, 0, 0);
}

static __device__ __forceinline__ short f2bf(float f) {
  __hip_bfloat16 h = __float2bfloat16(f);
  return *reinterpret_cast<short*>(&h);
}

// ---------------- K1: offset conv (round-8 proven) ----------------
__global__ __launch_bounds__(256, 4) void offset_conv_kernel(
    const float* __restrict__ x, const float* __restrict__ ow,
    const float* __restrict__ ob, float* __restrict__ offp) {
  __shared__ __align__(16) float lds_w[16 * 9 * 12];   // [ci][ch][12 (9 taps + pad)]
  int blk = blockIdx.x;                     // 0..1023
  int r = blk & 63, seg = (blk >> 6) & 7, chalf = blk >> 9;
  int tid = threadIdx.x;
  for (int i = tid; i < 16 * 9 * 12; i += 256) {
    int t = i % 12;
    int rem = i / 12;                       // ci*9 + ch
    int ch = rem % 9, ci = rem / 9;
    lds_w[i] = (t < 9) ? ow[(chalf * 9 + ch) * KTOT + (seg * 16 + ci) * 9 + t] : 0.f;
  }
  __syncthreads();

  int v = r * 256 + tid;                    // 0..16383
  int wp = v & 31, ho = (v >> 5) & 63, b = v >> 11;
  int wo0 = wp * 2;
  float acc0[9], acc1[9];
#pragma unroll
  for (int c = 0; c < 9; ++c) { acc0[c] = 0.f; acc1[c] = 0.f; }
  const float* xb = x + (b * CIN + seg * 16) * HW;
  for (int ci = 0; ci < 16; ++ci) {
    const float* xp = xb + ci * HW;
    float win[3][4];
#pragma unroll
    for (int ky = 0; ky < 3; ++ky) {
      int iy = ho - 1 + ky;
      bool rok = (iy >= 0) & (iy < Hx);
      const float* rowp = xp + iy * Wx;
#pragma unroll
      for (int c = 0; c < 4; ++c) {
        int ix = wo0 - 1 + c;
        win[ky][c] = (rok & (ix >= 0) & (ix < Wx)) ? rowp[ix] : 0.f;
      }
    }
    const float4* wq = (const float4*)&lds_w[ci * 108];
#pragma unroll
    for (int ch = 0; ch < 9; ++ch) {
      float4 w0 = wq[ch * 3 + 0];
      float4 w1 = wq[ch * 3 + 1];
      float4 w2 = wq[ch * 3 + 2];
      float a0 = acc0[ch], a1 = acc1[ch];
      a0 = fmaf(win[0][0], w0.x, a0); a1 = fmaf(win[0][1], w0.x, a1);
      a0 = fmaf(win[0][1], w0.y, a0); a1 = fmaf(win[0][2], w0.y, a1);
      a0 = fmaf(win[0][2], w0.z, a0); a1 = fmaf(win[0][3], w0.z, a1);
      a0 = fmaf(win[1][0], w0.w, a0); a1 = fmaf(win[1][1], w0.w, a1);
      a0 = fmaf(win[1][1], w1.x, a0); a1 = fmaf(win[1][2], w1.x, a1);
      a0 = fmaf(win[1][2], w1.y, a0); a1 = fmaf(win[1][3], w1.y, a1);
      a0 = fmaf(win[2][0], w1.z, a0); a1 = fmaf(win[2][1], w1.z, a1);
      a0 = fmaf(win[2][1], w1.w, a0); a1 = fmaf(win[2][2], w1.w, a1);
      a0 = fmaf(win[2][2], w2.x, a0); a1 = fmaf(win[2][3], w2.x, a1);
      acc0[ch] = a0; acc1[ch] = a1;
    }
  }
  float* op = offp + seg * OFFSEG + (b * NOFF + chalf * 9) * HW + ho * 64 + wo0;
#pragma unroll
  for (int c = 0; c < 9; ++c) {
    float bias = (seg == 0) ? ob[chalf * 9 + c] : 0.f;
    op[c * HW]     = acc0[c] + bias;
    op[c * HW + 1] = acc1[c] + bias;
  }
}

// ---------------- K2: weight -> bf16 blocked Wb[kc][cout][32] (proven) ----------------
__global__ __launch_bounds__(256) void wt_cvt_kernel(
    const float* __restrict__ w, short* __restrict__ Wb) {
  int t = blockIdx.x * 256 + threadIdx.x;   // 294912
  int ki = t & 31;
  int cout = (t >> 5) & 255;
  int kc = t >> 13;                         // 0..35
  int k = kc * 32 + ki;
  int kk = k >> 7, cin = k & 127;
  Wb[t] = f2bf(w[(cout * CIN + cin) * 9 + kk]);
}

// ---------------- K3: bilinear coefficient tables (proven, 8 partials) ----------------
__global__ __launch_bounds__(256) void coeff_kernel(
    const float* __restrict__ offp, short4* __restrict__ cidx, float4* __restrict__ cwt) {
  int t = blockIdx.x * 256 + threadIdx.x;   // 9*32768
  int m = t & (M_ - 1);
  int kk = t >> 15;                         // 0..8
  int b = m >> 12, ho = (m >> 6) & 63, wo = m & 63;
  int base = (b * NOFF + 2 * kk) * HW + (m & 4095);
  int base2 = base + HW;
  float dy = 0.f, dx = 0.f;
#pragma unroll
  for (int s = 0; s < 8; ++s) {
    dy += offp[base + s * OFFSEG];
    dx += offp[base2 + s * OFFSEG];
  }
  float sy = (float)(ho - 1 + kk / 3) + dy;
  float sx = (float)(wo - 1 + kk % 3) + dx;
  float fy = floorf(sy), fx = floorf(sx);
  int y0 = (int)fy, x0 = (int)fx;
  float wy = sy - fy, wx = sx - fx;
  int y1 = y0 + 1, x1 = x0 + 1;
  int cy0 = min(max(y0, 0), Hx - 1), cy1 = min(max(y1, 0), Hx - 1);
  int cx0 = min(max(x0, 0), Wx - 1), cx1 = min(max(x1, 0), Wx - 1);
  bool vy0 = (y0 >= 0) & (y0 < Hx), vy1 = (y1 >= 0) & (y1 < Hx);
  bool vx0 = (x0 >= 0) & (x0 < Wx), vx1 = (x1 >= 0) & (x1 < Wx);
  short4 id;
  id.x = (short)(cy0 * Wx + cx0); id.y = (short)(cy0 * Wx + cx1);
  id.z = (short)(cy1 * Wx + cx0); id.w = (short)(cy1 * Wx + cx1);
  float4 wv;
  wv.x = (vy0 && vx0) ? (1.f - wy) * (1.f - wx) : 0.f;
  wv.y = (vy0 && vx1) ? (1.f - wy) * wx : 0.f;
  wv.z = (vy1 && vx0) ? wy * (1.f - wx) : 0.f;
  wv.w = (vy1 && vx1) ? wy * wx : 0.f;
  cidx[t] = id;
  cwt[t] = wv;
}

// ---------------- K4: LDS-plane sampler, v2 ----------------
// Changes vs v1 (78 us, Occupancy 9.7%, all pipes idle -> latency-bound):
//  * 512-thread blocks + __launch_bounds__(512,4): VGPR capped at 128 so
//    2 blocks/CU co-reside -> 16 waves/CU (was 8). LDS 2*64KB=128KB <= 160KB.
//  * x planes staged as float2 PAIRS ({cin0,cin1} and {cin2,cin3} per pixel):
//    each bilinear corner is ONE ds_read_b64 per pair -> 8 LDS reads/sample
//    instead of 16 b32 reads. Halves the LDS pipe floor (~22us -> ~13us) and
//    halves the number of latency events to hide.
// blk = (khalf<<8)|(g4<<3)|b, grid 512 unchanged. Pb layout unchanged.
__global__ __launch_bounds__(512, 4) void sampler_kernel(
    const float* __restrict__ x, const short4* __restrict__ cidx,
    const float4* __restrict__ cwt, short* __restrict__ Pb) {
  __shared__ __align__(16) float2 lds2[2][HW];   // 65536 B: [pair][pixel]{cinA,cinB}
  int blk = blockIdx.x;                     // 0..511
  int b = blk & 7;
  int g4 = (blk >> 3) & 31;                 // 0..31
  int khalf = blk >> 8;
  int cinq = g4 >> 3;                       // cin-quarter within chunk group
  int e = g4 & 7;                           // 4-cin slot within chunk
  int tid = threadIdx.x;                    // 0..511

  // stage 4 planes, interleaved into two float2 pair-arrays.
  // lane-contiguous float4 LDS writes (16B stride) -> conflict-free.
  const float* xp = x + (b * CIN + g4 * 4) * HW;
  const float2* pl0 = (const float2*)(xp);
  const float2* pl1 = (const float2*)(xp + HW);
  const float2* pl2 = (const float2*)(xp + 2 * HW);
  const float2* pl3 = (const float2*)(xp + 3 * HW);
  float4* q0 = (float4*)&lds2[0][0];
  float4* q1 = (float4*)&lds2[1][0];
#pragma unroll
  for (int it = 0; it < 4; ++it) {
    int j = it * 512 + tid;                 // float2-pixel-pair index 0..2047
    float2 a  = pl0[j];
    float2 b2 = pl1[j];
    float2 c2 = pl2[j];
    float2 d2 = pl3[j];
    float4 w0; w0.x = a.x;  w0.y = b2.x; w0.z = a.y;  w0.w = b2.y;
    float4 w1; w1.x = c2.x; w1.y = d2.x; w1.z = c2.y; w1.w = d2.y;
    q0[j] = w0;                             // pixels 2j,2j+1 of pair (cin0,cin1)
    q1[j] = w1;                             // pixels 2j,2j+1 of pair (cin2,cin3)
  }
  __syncthreads();

  const float2* P0 = &lds2[0][0];
  const float2* P1 = &lds2[1][0];

  int kk0 = khalf ? 5 : 0;
  int kk1 = khalf ? 9 : 5;
  for (int kk = kk0; kk < kk1; ++kk) {
    int kcg = kk * 4 + cinq;                // 0..35
    const short4* cp = cidx + kk * M_ + b * HW;
    const float4* wp = cwt + kk * M_ + b * HW;
    short* pb = Pb + (kcg * M_ + b * HW) * 32 + e * 4;
#pragma unroll 2
    for (int it = 0; it < 8; ++it) {
      int pos = it * 512 + tid;
      short4 id = cp[pos];
      float4 wv = wp[pos];
      float2 a0 = P0[(int)id.x], b0 = P0[(int)id.y];
      float2 c0 = P0[(int)id.z], d0 = P0[(int)id.w];
      float2 a1 = P1[(int)id.x], b1 = P1[(int)id.y];
      float2 c1 = P1[(int)id.z], d1 = P1[(int)id.w];
      float s0 = wv.x * a0.x + wv.y * b0.x + wv.z * c0.x + wv.w * d0.x;
      float s1 = wv.x * a0.y + wv.y * b0.y + wv.z * c0.y + wv.w * d0.y;
      float s2 = wv.x * a1.x + wv.y * b1.x + wv.z * c1.x + wv.w * d1.x;
      float s3 = wv.x * a1.y + wv.y * b1.y + wv.z * c1.y + wv.w * d1.y;
      union { short s[4]; int2 v; } bu;
      bu.s[0] = f2bf(s0); bu.s[1] = f2bf(s1);
      bu.s[2] = f2bf(s2); bu.s[3] = f2bf(s3);
      *(int2*)&pb[pos * 32] = bu.v;
    }
  }
}

// ---------------- K5: single bf16 MFMA GEMM, m97-style async K-loop ----------------
// blk: mt = blk&255, ct = blk>>8 (ct-pair shares XCD -> Pb L2 reuse).
// Tile 128 cout x 128 m, K=1152 in 36 chunks of 32. Double-buffered 16KB LDS
// tiles staged by global_load_lds (flat 8KB A + 8KB B copies); ONE barrier per
// chunk; next chunk's DMA flies across the 16 MFMAs.
__global__ __launch_bounds__(256, 2) void gemm_kernel(
    const short* __restrict__ Wb, const short* __restrict__ Pb,
    float* __restrict__ y) {
  __shared__ __align__(16) short lds[2][8192];   // [buf][ A 4096 | B 4096 ] shorts

  int tid = threadIdx.x;
  int mt = blockIdx.x & 255;
  int ct = blockIdx.x >> 8;
  int cout0 = ct * 128;
  int m0 = mt * 128;

  int lane = tid & 63, wave = tid >> 6;
  int quad = lane >> 4, l16 = lane & 15;
  int wm = (wave & 1) << 6;          // cout sub-tile 0/64
  int wnm = (wave >> 1) << 6;        // m sub-tile 0/64

  // staging roles: waves 0,1 -> A halves; waves 2,3 -> B halves
  int isB = wave >> 1;
  int sub = wave & 1;
  const short* srcbase = isB ? (Pb + m0 * 32) : (Wb + cout0 * 32);
  const int sstride = isB ? (M_ * 32) : (256 * 32);
  const int soff = sub * 2048 + lane * 8;        // shorts
  const int doff = isB * 4096 + sub * 2048 + lane * 8;

  f32x4 zero = {0.f, 0.f, 0.f, 0.f};
  f32x4 acc[4][4];
#pragma unroll
  for (int i = 0; i < 4; ++i)
#pragma unroll
    for (int j = 0; j < 4; ++j) acc[i][j] = zero;

  // prologue: chunk 0 -> buf 0
  {
    const short* s = srcbase + soff;
    short* d = &lds[0][doff];
#pragma unroll
    for (int j = 0; j < 4; ++j)
      async_cp16(s + j * 512, d + j * 512);
  }

  for (int ch = 0; ch < NCH; ++ch) {
    int p = ch & 1;
    __syncthreads();                 // drains DMA -> buf p ready; frag reads of p^1 done
    if (ch < NCH - 1) {
      const short* s = srcbase + (ch + 1) * sstride + soff;
      short* d = &lds[p ^ 1][doff];
#pragma unroll
      for (int j = 0; j < 4; ++j)
        async_cp16(s + j * 512, d + j * 512);   // flies across the MFMAs below
    }
    const short* sa = &lds[p][0];
    const short* sb = &lds[p][4096];
    bf16x8 af[4], bfr[4];
#pragma unroll
    for (int i = 0; i < 4; ++i)
      af[i] = *(const bf16x8*)&sa[(wm + i * 16 + l16) * 32 + quad * 8];
#pragma unroll
    for (int j = 0; j < 4; ++j)
      bfr[j] = *(const bf16x8*)&sb[(wnm + j * 16 + l16) * 32 + quad * 8];
#pragma unroll
    for (int i = 0; i < 4; ++i)
#pragma unroll
      for (int j = 0; j < 4; ++j)
        acc[i][j] = __builtin_amdgcn_mfma_f32_16x16x32_bf16(af[i], bfr[j], acc[i][j], 0, 0, 0);
  }

  // epilogue: write y once (dconv bias cancels in BN mean-subtraction)
#pragma unroll
  for (int i = 0; i < 4; ++i) {
    int crow = cout0 + wm + i * 16 + quad * 4;
#pragma unroll
    for (int j = 0; j < 4; ++j) {
      int m = m0 + wnm + j * 16 + l16;
      int b = m >> 12;
      float* yp = y + (b * COUT + crow) * HW + (m & 4095);
#pragma unroll
      for (int r2 = 0; r2 < 4; ++r2)
        yp[r2 * HW] = acc[i][j][r2];
    }
  }
}

// ---------------- K6: BN batch stats (proven) ----------------
__global__ __launch_bounds__(256) void bn_stats_kernel(
    const float* __restrict__ y, float* __restrict__ mean, float* __restrict__ invstd) {
  int c = blockIdx.x;
  int tid = threadIdx.x;
  float s = 0.f, s2 = 0.f;
  for (int b = 0; b < B_; ++b) {
    const float4* p = (const float4*)(y + (b * COUT + c) * HW);
    for (int i = tid; i < HW / 4; i += 256) {
      float4 v = p[i];
      s += v.x + v.y + v.z + v.w;
      s2 = fmaf(v.x, v.x, s2); s2 = fmaf(v.y, v.y, s2);
      s2 = fmaf(v.z, v.z, s2); s2 = fmaf(v.w, v.w, s2);
    }
  }
#pragma unroll
  for (int o = 32; o > 0; o >>= 1) {
    s  += __shfl_down(s, o);
    s2 += __shfl_down(s2, o);
  }
  __shared__ float rs[4], rs2[4];
  int wid = tid >> 6, ln = tid & 63;
  if (ln == 0) { rs[wid] = s; rs2[wid] = s2; }
  __syncthreads();
  if (tid == 0) {
    float S  = rs[0] + rs[1] + rs[2] + rs[3];
    float S2 = rs2[0] + rs2[1] + rs2[2] + rs2[3];
    float m = S / 32768.f;
    float var = S2 / 32768.f - m * m;
    mean[c] = m;
    invstd[c] = rsqrtf(var + 1e-5f);
  }
}

// ---------------- K7: BN apply + SiLU, in place on y (= d_out) (proven) ----------------
__global__ __launch_bounds__(256) void bn_silu_kernel(
    float* __restrict__ y, const float* __restrict__ mean,
    const float* __restrict__ invstd, const float* __restrict__ gamma,
    const float* __restrict__ beta) {
  int i4 = blockIdx.x * 256 + threadIdx.x;   // 2097152 float4s
  int c = (i4 >> 10) & 255;
  float4 v = ((const float4*)y)[i4];
  float m = mean[c], sc = invstd[c] * gamma[c], bt = beta[c];
  float t0 = (v.x - m) * sc + bt;
  float t1 = (v.y - m) * sc + bt;
  float t2 = (v.z - m) * sc + bt;
  float t3 = (v.w - m) * sc + bt;
  float4 o;
  o.x = t0 / (1.f + expf(-t0));
  o.y = t1 / (1.f + expf(-t1));
  o.z = t2 / (1.f + expf(-t2));
  o.w = t3 / (1.f + expf(-t3));
  ((float4*)y)[i4] = o;
}

extern "C" void kernel_launch(void* const* d_in, const int* in_sizes, int n_in,
                              void* d_out, int out_size, void* d_ws, size_t ws_size,
                              hipStream_t stream) {
  const float* x     = (const float*)d_in[0];
  const float* ow    = (const float*)d_in[1];
  const float* ob    = (const float*)d_in[2];
  const float* dw    = (const float*)d_in[3];
  // d_in[4] = dconv bias: cancelled exactly by BN mean-subtraction
  const float* gamma = (const float*)d_in[5];
  const float* beta  = (const float*)d_in[6];
  float* y = (float*)d_out;                  // 8*256*4096 f32 — y buffer, finished in place

  // ws layout (float offsets), total 25,510,400 floats = 102.0 MB (ws = 256 MiB)
  float*  ws   = (float*)d_ws;
  short*  Pb   = (short*)ws;                 // 36*32768*32 shorts = 18874368 floats
  float*  offp = ws + 18874368;              // 8 * 589824 = 4718592
  short4* cidx = (short4*)(ws + 23592960);   // 9*32768 short4 = 589824 floats
  float4* cwt  = (float4*)(ws + 24182784);   // 9*32768 float4 = 1179648 floats
  short*  Wb   = (short*)(ws + 25362432);    // 294912 shorts = 147456 floats
  float*  mean   = ws + 25509888;            // 256
  float*  invstd = ws + 25510144;            // 256

  offset_conv_kernel<<<1024, 256, 0, stream>>>(x, ow, ob, offp);
  wt_cvt_kernel<<<1152, 256, 0, stream>>>(dw, Wb);
  coeff_kernel<<<1152, 256, 0, stream>>>(offp, cidx, cwt);
  sampler_kernel<<<512, 512, 0, stream>>>(x, cidx, cwt, Pb);
  gemm_kernel<<<512, 256, 0, stream>>>(Wb, Pb, y);
  bn_stats_kernel<<<256, 256, 0, stream>>>(y, mean, invstd);
  bn_silu_kernel<<<8192, 256, 0, stream>>>(y, mean, invstd, gamma, beta);
}

// Round 3
// 262.398 us; speedup vs baseline: 1.2610x; 1.2610x over previous
//
#include <hip/hip_runtime.h>
#include <hip/hip_bf16.h>
#include <math.h>

// (B,Cin,H,W)=(8,128,64,64), Cout=256, K=3, stride=1, pad=1, dil=1
#define B_    8
#define CIN   128
#define Hx    64
#define Wx    64
#define COUT  256
#define HW    4096
#define KTOT  1152      // CIN*9
#define NOFF  18
#define M_    32768     // B*HW
#define OFFSEG (B_ * NOFF * HW)   // 589824 floats per cin-segment partial
#define NCH   36        // K-chunks (chunk = 32 k)

typedef short bf16x8 __attribute__((ext_vector_type(8)));
typedef float f32x4  __attribute__((ext_vector_type(4)));

typedef __attribute__((address_space(1))) const unsigned int gu32;
typedef __attribute__((address_space(3))) unsigned int lu32;
static __device__ __forceinline__ void async_cp16(const short* g, short* l) {
  __builtin_amdgcn_global_load_lds((gu32*)g, (lu32*)l, 16, 0, 0);
}

static __device__ __forceinline__ short f2bf(float f) {
  __hip_bfloat16 h = __float2bfloat16(f);
  return *reinterpret_cast<short*>(&h);
}

// ---------------- K1: offset conv (round-8 proven) ----------------
__global__ __launch_bounds__(256, 4) void offset_conv_kernel(
    const float* __restrict__ x, const float* __restrict__ ow,
    const float* __restrict__ ob, float* __restrict__ offp) {
  __shared__ __align__(16) float lds_w[16 * 9 * 12];   // [ci][ch][12 (9 taps + pad)]
  int blk = blockIdx.x;                     // 0..1023
  int r = blk & 63, seg = (blk >> 6) & 7, chalf = blk >> 9;
  int tid = threadIdx.x;
  for (int i = tid; i < 16 * 9 * 12; i += 256) {
    int t = i % 12;
    int rem = i / 12;                       // ci*9 + ch
    int ch = rem % 9, ci = rem / 9;
    lds_w[i] = (t < 9) ? ow[(chalf * 9 + ch) * KTOT + (seg * 16 + ci) * 9 + t] : 0.f;
  }
  __syncthreads();

  int v = r * 256 + tid;                    // 0..16383
  int wp = v & 31, ho = (v >> 5) & 63, b = v >> 11;
  int wo0 = wp * 2;
  float acc0[9], acc1[9];
#pragma unroll
  for (int c = 0; c < 9; ++c) { acc0[c] = 0.f; acc1[c] = 0.f; }
  const float* xb = x + (b * CIN + seg * 16) * HW;
  for (int ci = 0; ci < 16; ++ci) {
    const float* xp = xb + ci * HW;
    float win[3][4];
#pragma unroll
    for (int ky = 0; ky < 3; ++ky) {
      int iy = ho - 1 + ky;
      bool rok = (iy >= 0) & (iy < Hx);
      const float* rowp = xp + iy * Wx;
#pragma unroll
      for (int c = 0; c < 4; ++c) {
        int ix = wo0 - 1 + c;
        win[ky][c] = (rok & (ix >= 0) & (ix < Wx)) ? rowp[ix] : 0.f;
      }
    }
    const float4* wq = (const float4*)&lds_w[ci * 108];
#pragma unroll
    for (int ch = 0; ch < 9; ++ch) {
      float4 w0 = wq[ch * 3 + 0];
      float4 w1 = wq[ch * 3 + 1];
      float4 w2 = wq[ch * 3 + 2];
      float a0 = acc0[ch], a1 = acc1[ch];
      a0 = fmaf(win[0][0], w0.x, a0); a1 = fmaf(win[0][1], w0.x, a1);
      a0 = fmaf(win[0][1], w0.y, a0); a1 = fmaf(win[0][2], w0.y, a1);
      a0 = fmaf(win[0][2], w0.z, a0); a1 = fmaf(win[0][3], w0.z, a1);
      a0 = fmaf(win[1][0], w0.w, a0); a1 = fmaf(win[1][1], w0.w, a1);
      a0 = fmaf(win[1][1], w1.x, a0); a1 = fmaf(win[1][2], w1.x, a1);
      a0 = fmaf(win[1][2], w1.y, a0); a1 = fmaf(win[1][3], w1.y, a1);
      a0 = fmaf(win[2][0], w1.z, a0); a1 = fmaf(win[2][1], w1.z, a1);
      a0 = fmaf(win[2][1], w1.w, a0); a1 = fmaf(win[2][2], w1.w, a1);
      a0 = fmaf(win[2][2], w2.x, a0); a1 = fmaf(win[2][3], w2.x, a1);
      acc0[ch] = a0; acc1[ch] = a1;
    }
  }
  float* op = offp + seg * OFFSEG + (b * NOFF + chalf * 9) * HW + ho * 64 + wo0;
#pragma unroll
  for (int c = 0; c < 9; ++c) {
    float bias = (seg == 0) ? ob[chalf * 9 + c] : 0.f;
    op[c * HW]     = acc0[c] + bias;
    op[c * HW + 1] = acc1[c] + bias;
  }
}

// ---------------- K2: weight -> bf16 blocked Wb[kc][cout][32] (proven) ----------------
__global__ __launch_bounds__(256) void wt_cvt_kernel(
    const float* __restrict__ w, short* __restrict__ Wb) {
  int t = blockIdx.x * 256 + threadIdx.x;   // 294912
  int ki = t & 31;
  int cout = (t >> 5) & 255;
  int kc = t >> 13;                         // 0..35
  int k = kc * 32 + ki;
  int kk = k >> 7, cin = k & 127;
  Wb[t] = f2bf(w[(cout * CIN + cin) * 9 + kk]);
}

// ---------------- K3: bilinear coefficient tables (proven, 8 partials) ----------------
__global__ __launch_bounds__(256) void coeff_kernel(
    const float* __restrict__ offp, short4* __restrict__ cidx, float4* __restrict__ cwt) {
  int t = blockIdx.x * 256 + threadIdx.x;   // 9*32768
  int m = t & (M_ - 1);
  int kk = t >> 15;                         // 0..8
  int b = m >> 12, ho = (m >> 6) & 63, wo = m & 63;
  int base = (b * NOFF + 2 * kk) * HW + (m & 4095);
  int base2 = base + HW;
  float dy = 0.f, dx = 0.f;
#pragma unroll
  for (int s = 0; s < 8; ++s) {
    dy += offp[base + s * OFFSEG];
    dx += offp[base2 + s * OFFSEG];
  }
  float sy = (float)(ho - 1 + kk / 3) + dy;
  float sx = (float)(wo - 1 + kk % 3) + dx;
  float fy = floorf(sy), fx = floorf(sx);
  int y0 = (int)fy, x0 = (int)fx;
  float wy = sy - fy, wx = sx - fx;
  int y1 = y0 + 1, x1 = x0 + 1;
  int cy0 = min(max(y0, 0), Hx - 1), cy1 = min(max(y1, 0), Hx - 1);
  int cx0 = min(max(x0, 0), Wx - 1), cx1 = min(max(x1, 0), Wx - 1);
  bool vy0 = (y0 >= 0) & (y0 < Hx), vy1 = (y1 >= 0) & (y1 < Hx);
  bool vx0 = (x0 >= 0) & (x0 < Wx), vx1 = (x1 >= 0) & (x1 < Wx);
  short4 id;
  id.x = (short)(cy0 * Wx + cx0); id.y = (short)(cy0 * Wx + cx1);
  id.z = (short)(cy1 * Wx + cx0); id.w = (short)(cy1 * Wx + cx1);
  float4 wv;
  wv.x = (vy0 && vx0) ? (1.f - wy) * (1.f - wx) : 0.f;
  wv.y = (vy0 && vx1) ? (1.f - wy) * wx : 0.f;
  wv.z = (vy1 && vx0) ? wy * (1.f - wx) : 0.f;
  wv.w = (vy1 && vx1) ? wy * wx : 0.f;
  cidx[t] = id;
  cwt[t] = wv;
}

// ---------------- K4: LDS-plane sampler, v3 (resubmit — container flake) ----------------
// Post-mortem v2 (179us): occupancy rose to 32% but VGPR fell to 52 and
// VALUBusy fell to 4.8% -> launch_bounds(512,4) + unroll-2 destroyed the
// deep full-unroll pipeline that made v1 (78us, VGPR 140) work. v3 keeps
// v1's EXACT inner-loop shape (256 thr, full unroll 16, gather->fma->store)
// and buys occupancy on the LDS axis instead:
//  * 2 planes/block staged as interleaved float2[HW] = 32KB LDS
//    -> launch_bounds(256,4): 4 blocks/CU = 16 waves/CU (v1: 2 blocks, 8).
//  * one ds_read_b64 per bilinear corner serves BOTH cins -> 4 LDS
//    reads/sample for 2 cins (v1: 16 b32 for 4 cins) = half the reads/cin.
//  * per-iter live regs ~half of v1 -> full unroll fits the 128-VGPR cap.
// blk = (khalf<<9)|(g2<<3)|b, grid 1024. Pb layout unchanged (4B int store
// at slot e2*2 shorts).
__global__ __launch_bounds__(256, 4) void sampler_kernel(
    const float* __restrict__ x, const short4* __restrict__ cidx,
    const float4* __restrict__ cwt, short* __restrict__ Pb) {
  __shared__ __align__(16) float2 ldsp[HW];   // 32768 B: [pixel]{cinA,cinB}
  int blk = blockIdx.x;                     // 0..1023
  int b = blk & 7;
  int g2 = (blk >> 3) & 63;                 // cin-pair 0..63
  int khalf = blk >> 9;
  int cinq = g2 >> 4;                       // cin-quarter (chunk) 0..3
  int e2 = g2 & 15;                         // pair slot within chunk 0..15
  int tid = threadIdx.x;

  // stage 2 planes interleaved: ldsp[pix] = {planeA[pix], planeB[pix]}
  const float2* pl0 = (const float2*)(x + (b * CIN + g2 * 2) * HW);
  const float2* pl1 = (const float2*)(x + (b * CIN + g2 * 2 + 1) * HW);
  float4* q = (float4*)ldsp;
#pragma unroll
  for (int it = 0; it < 8; ++it) {
    int j = it * 256 + tid;                 // float2-pixel-pair index 0..2047
    float2 a = pl0[j];
    float2 c = pl1[j];
    float4 w; w.x = a.x; w.y = c.x; w.z = a.y; w.w = c.y;
    q[j] = w;                               // pixels 2j, 2j+1
  }
  __syncthreads();

  int kk0 = khalf ? 5 : 0;
  int kk1 = khalf ? 9 : 5;
  for (int kk = kk0; kk < kk1; ++kk) {
    int kcg = kk * 4 + cinq;                // 0..35
    const short4* cp = cidx + kk * M_ + b * HW;
    const float4* wp = cwt + kk * M_ + b * HW;
    short* pb = Pb + (kcg * M_ + b * HW) * 32 + e2 * 2;
#pragma unroll
    for (int it = 0; it < 16; ++it) {
      int pos = it * 256 + tid;
      short4 id = cp[pos];
      float4 wv = wp[pos];
      float2 va = ldsp[(int)id.x];
      float2 vb = ldsp[(int)id.y];
      float2 vc = ldsp[(int)id.z];
      float2 vd = ldsp[(int)id.w];
      float s0 = wv.x * va.x + wv.y * vb.x + wv.z * vc.x + wv.w * vd.x;
      float s1 = wv.x * va.y + wv.y * vb.y + wv.z * vc.y + wv.w * vd.y;
      union { short s[2]; int v; } bu;
      bu.s[0] = f2bf(s0);
      bu.s[1] = f2bf(s1);
      *(int*)&pb[pos * 32] = bu.v;
    }
  }
}

// ---------------- K5: single bf16 MFMA GEMM, m97-style async K-loop ----------------
// blk: mt = blk&255, ct = blk>>8 (ct-pair shares XCD -> Pb L2 reuse).
// Tile 128 cout x 128 m, K=1152 in 36 chunks of 32. Double-buffered 16KB LDS
// tiles staged by global_load_lds (flat 8KB A + 8KB B copies); ONE barrier per
// chunk; next chunk's DMA flies across the 16 MFMAs.
__global__ __launch_bounds__(256, 2) void gemm_kernel(
    const short* __restrict__ Wb, const short* __restrict__ Pb,
    float* __restrict__ y) {
  __shared__ __align__(16) short lds[2][8192];   // [buf][ A 4096 | B 4096 ] shorts

  int tid = threadIdx.x;
  int mt = blockIdx.x & 255;
  int ct = blockIdx.x >> 8;
  int cout0 = ct * 128;
  int m0 = mt * 128;

  int lane = tid & 63, wave = tid >> 6;
  int quad = lane >> 4, l16 = lane & 15;
  int wm = (wave & 1) << 6;          // cout sub-tile 0/64
  int wnm = (wave >> 1) << 6;        // m sub-tile 0/64

  // staging roles: waves 0,1 -> A halves; waves 2,3 -> B halves
  int isB = wave >> 1;
  int sub = wave & 1;
  const short* srcbase = isB ? (Pb + m0 * 32) : (Wb + cout0 * 32);
  const int sstride = isB ? (M_ * 32) : (256 * 32);
  const int soff = sub * 2048 + lane * 8;        // shorts
  const int doff = isB * 4096 + sub * 2048 + lane * 8;

  f32x4 zero = {0.f, 0.f, 0.f, 0.f};
  f32x4 acc[4][4];
#pragma unroll
  for (int i = 0; i < 4; ++i)
#pragma unroll
    for (int j = 0; j < 4; ++j) acc[i][j] = zero;

  // prologue: chunk 0 -> buf 0
  {
    const short* s = srcbase + soff;
    short* d = &lds[0][doff];
#pragma unroll
    for (int j = 0; j < 4; ++j)
      async_cp16(s + j * 512, d + j * 512);
  }

  for (int ch = 0; ch < NCH; ++ch) {
    int p = ch & 1;
    __syncthreads();                 // drains DMA -> buf p ready; frag reads of p^1 done
    if (ch < NCH - 1) {
      const short* s = srcbase + (ch + 1) * sstride + soff;
      short* d = &lds[p ^ 1][doff];
#pragma unroll
      for (int j = 0; j < 4; ++j)
        async_cp16(s + j * 512, d + j * 512);   // flies across the MFMAs below
    }
    const short* sa = &lds[p][0];
    const short* sb = &lds[p][4096];
    bf16x8 af[4], bfr[4];
#pragma unroll
    for (int i = 0; i < 4; ++i)
      af[i] = *(const bf16x8*)&sa[(wm + i * 16 + l16) * 32 + quad * 8];
#pragma unroll
    for (int j = 0; j < 4; ++j)
      bfr[j] = *(const bf16x8*)&sb[(wnm + j * 16 + l16) * 32 + quad * 8];
#pragma unroll
    for (int i = 0; i < 4; ++i)
#pragma unroll
      for (int j = 0; j < 4; ++j)
        acc[i][j] = __builtin_amdgcn_mfma_f32_16x16x32_bf16(af[i], bfr[j], acc[i][j], 0, 0, 0);
  }

  // epilogue: write y once (dconv bias cancels in BN mean-subtraction)
#pragma unroll
  for (int i = 0; i < 4; ++i) {
    int crow = cout0 + wm + i * 16 + quad * 4;
#pragma unroll
    for (int j = 0; j < 4; ++j) {
      int m = m0 + wnm + j * 16 + l16;
      int b = m >> 12;
      float* yp = y + (b * COUT + crow) * HW + (m & 4095);
#pragma unroll
      for (int r2 = 0; r2 < 4; ++r2)
        yp[r2 * HW] = acc[i][j][r2];
    }
  }
}

// ---------------- K6: BN batch stats (proven) ----------------
__global__ __launch_bounds__(256) void bn_stats_kernel(
    const float* __restrict__ y, float* __restrict__ mean, float* __restrict__ invstd) {
  int c = blockIdx.x;
  int tid = threadIdx.x;
  float s = 0.f, s2 = 0.f;
  for (int b = 0; b < B_; ++b) {
    const float4* p = (const float4*)(y + (b * COUT + c) * HW);
    for (int i = tid; i < HW / 4; i += 256) {
      float4 v = p[i];
      s += v.x + v.y + v.z + v.w;
      s2 = fmaf(v.x, v.x, s2); s2 = fmaf(v.y, v.y, s2);
      s2 = fmaf(v.z, v.z, s2); s2 = fmaf(v.w, v.w, s2);
    }
  }
#pragma unroll
  for (int o = 32; o > 0; o >>= 1) {
    s  += __shfl_down(s, o);
    s2 += __shfl_down(s2, o);
  }
  __shared__ float rs[4], rs2[4];
  int wid = tid >> 6, ln = tid & 63;
  if (ln == 0) { rs[wid] = s; rs2[wid] = s2; }
  __syncthreads();
  if (tid == 0) {
    float S  = rs[0] + rs[1] + rs[2] + rs[3];
    float S2 = rs2[0] + rs2[1] + rs2[2] + rs2[3];
    float m = S / 32768.f;
    float var = S2 / 32768.f - m * m;
    mean[c] = m;
    invstd[c] = rsqrtf(var + 1e-5f);
  }
}

// ---------------- K7: BN apply + SiLU, in place on y (= d_out) (proven) ----------------
__global__ __launch_bounds__(256) void bn_silu_kernel(
    float* __restrict__ y, const float* __restrict__ mean,
    const float* __restrict__ invstd, const float* __restrict__ gamma,
    const float* __restrict__ beta) {
  int i4 = blockIdx.x * 256 + threadIdx.x;   // 2097152 float4s
  int c = (i4 >> 10) & 255;
  float4 v = ((const float4*)y)[i4];
  float m = mean[c], sc = invstd[c] * gamma[c], bt = beta[c];
  float t0 = (v.x - m) * sc + bt;
  float t1 = (v.y - m) * sc + bt;
  float t2 = (v.z - m) * sc + bt;
  float t3 = (v.w - m) * sc + bt;
  float4 o;
  o.x = t0 / (1.f + expf(-t0));
  o.y = t1 / (1.f + expf(-t1));
  o.z = t2 / (1.f + expf(-t2));
  o.w = t3 / (1.f + expf(-t3));
  ((float4*)y)[i4] = o;
}

extern "C" void kernel_launch(void* const* d_in, const int* in_sizes, int n_in,
                              void* d_out, int out_size, void* d_ws, size_t ws_size,
                              hipStream_t stream) {
  const float* x     = (const float*)d_in[0];
  const float* ow    = (const float*)d_in[1];
  const float* ob    = (const float*)d_in[2];
  const float* dw    = (const float*)d_in[3];
  // d_in[4] = dconv bias: cancelled exactly by BN mean-subtraction
  const float* gamma = (const float*)d_in[5];
  const float* beta  = (const float*)d_in[6];
  float* y = (float*)d_out;                  // 8*256*4096 f32 — y buffer, finished in place

  // ws layout (float offsets), total 25,510,400 floats = 102.0 MB (ws = 256 MiB)
  float*  ws   = (float*)d_ws;
  short*  Pb   = (short*)ws;                 // 36*32768*32 shorts = 18874368 floats
  float*  offp = ws + 18874368;              // 8 * 589824 = 4718592
  short4* cidx = (short4*)(ws + 23592960);   // 9*32768 short4 = 589824 floats
  float4* cwt  = (float4*)(ws + 24182784);   // 9*32768 float4 = 1179648 floats
  short*  Wb   = (short*)(ws + 25362432);    // 294912 shorts = 147456 floats
  float*  mean   = ws + 25509888;            // 256
  float*  invstd = ws + 25510144;            // 256

  offset_conv_kernel<<<1024, 256, 0, stream>>>(x, ow, ob, offp);
  wt_cvt_kernel<<<1152, 256, 0, stream>>>(dw, Wb);
  coeff_kernel<<<1152, 256, 0, stream>>>(offp, cidx, cwt);
  sampler_kernel<<<1024, 256, 0, stream>>>(x, cidx, cwt, Pb);
  gemm_kernel<<<512, 256, 0, stream>>>(Wb, Pb, y);
  bn_stats_kernel<<<256, 256, 0, stream>>>(y, mean, invstd);
  bn_silu_kernel<<<8192, 256, 0, stream>>>(y, mean, invstd, gamma, beta);
}

// Round 4
// 258.917 us; speedup vs baseline: 1.2780x; 1.0134x over previous
//
#include <hip/hip_runtime.h>
#include <hip/hip_bf16.h>
#include <math.h>

// (B,Cin,H,W)=(8,128,64,64), Cout=256, K=3, stride=1, pad=1, dil=1
#define B_    8
#define CIN   128
#define Hx    64
#define Wx    64
#define COUT  256
#define HW    4096
#define KTOT  1152      // CIN*9
#define NOFF  18
#define M_    32768     // B*HW
#define OFFSEG (B_ * NOFF * HW)   // 589824 floats per cin-segment partial
#define NCH   36        // K-chunks (chunk = 32 k)

typedef short bf16x8 __attribute__((ext_vector_type(8)));
typedef float f32x4  __attribute__((ext_vector_type(4)));

typedef __attribute__((address_space(1))) const unsigned int gu32;
typedef __attribute__((address_space(3))) unsigned int lu32;
static __device__ __forceinline__ void async_cp16(const short* g, short* l) {
  __builtin_amdgcn_global_load_lds((gu32*)g, (lu32*)l, 16, 0, 0);
}

static __device__ __forceinline__ short f2bf(float f) {
  __hip_bfloat16 h = __float2bfloat16(f);
  return *reinterpret_cast<short*>(&h);
}

// ---------------- K1: offset conv (round-8 proven) ----------------
__global__ __launch_bounds__(256, 4) void offset_conv_kernel(
    const float* __restrict__ x, const float* __restrict__ ow,
    const float* __restrict__ ob, float* __restrict__ offp) {
  __shared__ __align__(16) float lds_w[16 * 9 * 12];   // [ci][ch][12 (9 taps + pad)]
  int blk = blockIdx.x;                     // 0..1023
  int r = blk & 63, seg = (blk >> 6) & 7, chalf = blk >> 9;
  int tid = threadIdx.x;
  for (int i = tid; i < 16 * 9 * 12; i += 256) {
    int t = i % 12;
    int rem = i / 12;                       // ci*9 + ch
    int ch = rem % 9, ci = rem / 9;
    lds_w[i] = (t < 9) ? ow[(chalf * 9 + ch) * KTOT + (seg * 16 + ci) * 9 + t] : 0.f;
  }
  __syncthreads();

  int v = r * 256 + tid;                    // 0..16383
  int wp = v & 31, ho = (v >> 5) & 63, b = v >> 11;
  int wo0 = wp * 2;
  float acc0[9], acc1[9];
#pragma unroll
  for (int c = 0; c < 9; ++c) { acc0[c] = 0.f; acc1[c] = 0.f; }
  const float* xb = x + (b * CIN + seg * 16) * HW;
  for (int ci = 0; ci < 16; ++ci) {
    const float* xp = xb + ci * HW;
    float win[3][4];
#pragma unroll
    for (int ky = 0; ky < 3; ++ky) {
      int iy = ho - 1 + ky;
      bool rok = (iy >= 0) & (iy < Hx);
      const float* rowp = xp + iy * Wx;
#pragma unroll
      for (int c = 0; c < 4; ++c) {
        int ix = wo0 - 1 + c;
        win[ky][c] = (rok & (ix >= 0) & (ix < Wx)) ? rowp[ix] : 0.f;
      }
    }
    const float4* wq = (const float4*)&lds_w[ci * 108];
#pragma unroll
    for (int ch = 0; ch < 9; ++ch) {
      float4 w0 = wq[ch * 3 + 0];
      float4 w1 = wq[ch * 3 + 1];
      float4 w2 = wq[ch * 3 + 2];
      float a0 = acc0[ch], a1 = acc1[ch];
      a0 = fmaf(win[0][0], w0.x, a0); a1 = fmaf(win[0][1], w0.x, a1);
      a0 = fmaf(win[0][1], w0.y, a0); a1 = fmaf(win[0][2], w0.y, a1);
      a0 = fmaf(win[0][2], w0.z, a0); a1 = fmaf(win[0][3], w0.z, a1);
      a0 = fmaf(win[1][0], w0.w, a0); a1 = fmaf(win[1][1], w0.w, a1);
      a0 = fmaf(win[1][1], w1.x, a0); a1 = fmaf(win[1][2], w1.x, a1);
      a0 = fmaf(win[1][2], w1.y, a0); a1 = fmaf(win[1][3], w1.y, a1);
      a0 = fmaf(win[2][0], w1.z, a0); a1 = fmaf(win[2][1], w1.z, a1);
      a0 = fmaf(win[2][1], w1.w, a0); a1 = fmaf(win[2][2], w1.w, a1);
      a0 = fmaf(win[2][2], w2.x, a0); a1 = fmaf(win[2][3], w2.x, a1);
      acc0[ch] = a0; acc1[ch] = a1;
    }
  }
  float* op = offp + seg * OFFSEG + (b * NOFF + chalf * 9) * HW + ho * 64 + wo0;
#pragma unroll
  for (int c = 0; c < 9; ++c) {
    float bias = (seg == 0) ? ob[chalf * 9 + c] : 0.f;
    op[c * HW]     = acc0[c] + bias;
    op[c * HW + 1] = acc1[c] + bias;
  }
}

// ---------------- K2: weight -> bf16 blocked Wb[kc][cout][32] (proven) ----------------
__global__ __launch_bounds__(256) void wt_cvt_kernel(
    const float* __restrict__ w, short* __restrict__ Wb) {
  int t = blockIdx.x * 256 + threadIdx.x;   // 294912
  int ki = t & 31;
  int cout = (t >> 5) & 255;
  int kc = t >> 13;                         // 0..35
  int k = kc * 32 + ki;
  int kk = k >> 7, cin = k & 127;
  Wb[t] = f2bf(w[(cout * CIN + cin) * 9 + kk]);
}

// ---------------- K3: bilinear coefficient tables (proven, 8 partials) ----------------
__global__ __launch_bounds__(256) void coeff_kernel(
    const float* __restrict__ offp, short4* __restrict__ cidx, float4* __restrict__ cwt) {
  int t = blockIdx.x * 256 + threadIdx.x;   // 9*32768
  int m = t & (M_ - 1);
  int kk = t >> 15;                         // 0..8
  int b = m >> 12, ho = (m >> 6) & 63, wo = m & 63;
  int base = (b * NOFF + 2 * kk) * HW + (m & 4095);
  int base2 = base + HW;
  float dy = 0.f, dx = 0.f;
#pragma unroll
  for (int s = 0; s < 8; ++s) {
    dy += offp[base + s * OFFSEG];
    dx += offp[base2 + s * OFFSEG];
  }
  float sy = (float)(ho - 1 + kk / 3) + dy;
  float sx = (float)(wo - 1 + kk % 3) + dx;
  float fy = floorf(sy), fx = floorf(sx);
  int y0 = (int)fy, x0 = (int)fx;
  float wy = sy - fy, wx = sx - fx;
  int y1 = y0 + 1, x1 = x0 + 1;
  int cy0 = min(max(y0, 0), Hx - 1), cy1 = min(max(y1, 0), Hx - 1);
  int cx0 = min(max(x0, 0), Wx - 1), cx1 = min(max(x1, 0), Wx - 1);
  bool vy0 = (y0 >= 0) & (y0 < Hx), vy1 = (y1 >= 0) & (y1 < Hx);
  bool vx0 = (x0 >= 0) & (x0 < Wx), vx1 = (x1 >= 0) & (x1 < Wx);
  short4 id;
  id.x = (short)(cy0 * Wx + cx0); id.y = (short)(cy0 * Wx + cx1);
  id.z = (short)(cy1 * Wx + cx0); id.w = (short)(cy1 * Wx + cx1);
  float4 wv;
  wv.x = (vy0 && vx0) ? (1.f - wy) * (1.f - wx) : 0.f;
  wv.y = (vy0 && vx1) ? (1.f - wy) * wx : 0.f;
  wv.z = (vy1 && vx0) ? wy * (1.f - wx) : 0.f;
  wv.w = (vy1 && vx1) ? wy * wx : 0.f;
  cidx[t] = id;
  cwt[t] = wv;
}

// ---------------- K4: LDS-plane sampler, v4 ----------------
// Post-mortem v3 (106us): halved LDS reads confirmed (bank conflicts
// 4.62M -> 2.31M) and occupancy 32%, but VGPR landed at 52 AGAIN (= v2).
// Diagnosis: the __launch_bounds__ min-waves arg (128-VGPR cap) makes the
// allocator abandon cross-iteration pipelining entirely (v1 uncapped ->
// 140 VGPR deep pipeline, 78us on only 8 waves). v4 = v3 structure with
// the cap REMOVED: expect ~140 VGPR -> 3 blocks/CU (VGPR-limited; LDS
// 32KB would allow 5) = 12 waves/CU, 1.5x v1, with half of v1's LDS
// reads per cin. One variable changed vs v3.
// blk = (khalf<<9)|(g2<<3)|b, grid 1024. Pb layout unchanged (4B int
// store at slot e2*2 shorts).
__global__ __launch_bounds__(256) void sampler_kernel(
    const float* __restrict__ x, const short4* __restrict__ cidx,
    const float4* __restrict__ cwt, short* __restrict__ Pb) {
  __shared__ __align__(16) float2 ldsp[HW];   // 32768 B: [pixel]{cinA,cinB}
  int blk = blockIdx.x;                     // 0..1023
  int b = blk & 7;
  int g2 = (blk >> 3) & 63;                 // cin-pair 0..63
  int khalf = blk >> 9;
  int cinq = g2 >> 4;                       // cin-quarter (chunk) 0..3
  int e2 = g2 & 15;                         // pair slot within chunk 0..15
  int tid = threadIdx.x;

  // stage 2 planes interleaved: ldsp[pix] = {planeA[pix], planeB[pix]}
  const float2* pl0 = (const float2*)(x + (b * CIN + g2 * 2) * HW);
  const float2* pl1 = (const float2*)(x + (b * CIN + g2 * 2 + 1) * HW);
  float4* q = (float4*)ldsp;
#pragma unroll
  for (int it = 0; it < 8; ++it) {
    int j = it * 256 + tid;                 // float2-pixel-pair index 0..2047
    float2 a = pl0[j];
    float2 c = pl1[j];
    float4 w; w.x = a.x; w.y = c.x; w.z = a.y; w.w = c.y;
    q[j] = w;                               // pixels 2j, 2j+1
  }
  __syncthreads();

  int kk0 = khalf ? 5 : 0;
  int kk1 = khalf ? 9 : 5;
  for (int kk = kk0; kk < kk1; ++kk) {
    int kcg = kk * 4 + cinq;                // 0..35
    const short4* cp = cidx + kk * M_ + b * HW;
    const float4* wp = cwt + kk * M_ + b * HW;
    short* pb = Pb + (kcg * M_ + b * HW) * 32 + e2 * 2;
#pragma unroll
    for (int it = 0; it < 16; ++it) {
      int pos = it * 256 + tid;
      short4 id = cp[pos];
      float4 wv = wp[pos];
      float2 va = ldsp[(int)id.x];
      float2 vb = ldsp[(int)id.y];
      float2 vc = ldsp[(int)id.z];
      float2 vd = ldsp[(int)id.w];
      float s0 = wv.x * va.x + wv.y * vb.x + wv.z * vc.x + wv.w * vd.x;
      float s1 = wv.x * va.y + wv.y * vb.y + wv.z * vc.y + wv.w * vd.y;
      union { short s[2]; int v; } bu;
      bu.s[0] = f2bf(s0);
      bu.s[1] = f2bf(s1);
      *(int*)&pb[pos * 32] = bu.v;
    }
  }
}

// ---------------- K5: single bf16 MFMA GEMM, m97-style async K-loop ----------------
// blk: mt = blk&255, ct = blk>>8 (ct-pair shares XCD -> Pb L2 reuse).
// Tile 128 cout x 128 m, K=1152 in 36 chunks of 32. Double-buffered 16KB LDS
// tiles staged by global_load_lds (flat 8KB A + 8KB B copies); ONE barrier per
// chunk; next chunk's DMA flies across the 16 MFMAs.
__global__ __launch_bounds__(256, 2) void gemm_kernel(
    const short* __restrict__ Wb, const short* __restrict__ Pb,
    float* __restrict__ y) {
  __shared__ __align__(16) short lds[2][8192];   // [buf][ A 4096 | B 4096 ] shorts

  int tid = threadIdx.x;
  int mt = blockIdx.x & 255;
  int ct = blockIdx.x >> 8;
  int cout0 = ct * 128;
  int m0 = mt * 128;

  int lane = tid & 63, wave = tid >> 6;
  int quad = lane >> 4, l16 = lane & 15;
  int wm = (wave & 1) << 6;          // cout sub-tile 0/64
  int wnm = (wave >> 1) << 6;        // m sub-tile 0/64

  // staging roles: waves 0,1 -> A halves; waves 2,3 -> B halves
  int isB = wave >> 1;
  int sub = wave & 1;
  const short* srcbase = isB ? (Pb + m0 * 32) : (Wb + cout0 * 32);
  const int sstride = isB ? (M_ * 32) : (256 * 32);
  const int soff = sub * 2048 + lane * 8;        // shorts
  const int doff = isB * 4096 + sub * 2048 + lane * 8;

  f32x4 zero = {0.f, 0.f, 0.f, 0.f};
  f32x4 acc[4][4];
#pragma unroll
  for (int i = 0; i < 4; ++i)
#pragma unroll
    for (int j = 0; j < 4; ++j) acc[i][j] = zero;

  // prologue: chunk 0 -> buf 0
  {
    const short* s = srcbase + soff;
    short* d = &lds[0][doff];
#pragma unroll
    for (int j = 0; j < 4; ++j)
      async_cp16(s + j * 512, d + j * 512);
  }

  for (int ch = 0; ch < NCH; ++ch) {
    int p = ch & 1;
    __syncthreads();                 // drains DMA -> buf p ready; frag reads of p^1 done
    if (ch < NCH - 1) {
      const short* s = srcbase + (ch + 1) * sstride + soff;
      short* d = &lds[p ^ 1][doff];
#pragma unroll
      for (int j = 0; j < 4; ++j)
        async_cp16(s + j * 512, d + j * 512);   // flies across the MFMAs below
    }
    const short* sa = &lds[p][0];
    const short* sb = &lds[p][4096];
    bf16x8 af[4], bfr[4];
#pragma unroll
    for (int i = 0; i < 4; ++i)
      af[i] = *(const bf16x8*)&sa[(wm + i * 16 + l16) * 32 + quad * 8];
#pragma unroll
    for (int j = 0; j < 4; ++j)
      bfr[j] = *(const bf16x8*)&sb[(wnm + j * 16 + l16) * 32 + quad * 8];
#pragma unroll
    for (int i = 0; i < 4; ++i)
#pragma unroll
      for (int j = 0; j < 4; ++j)
        acc[i][j] = __builtin_amdgcn_mfma_f32_16x16x32_bf16(af[i], bfr[j], acc[i][j], 0, 0, 0);
  }

  // epilogue: write y once (dconv bias cancels in BN mean-subtraction)
#pragma unroll
  for (int i = 0; i < 4; ++i) {
    int crow = cout0 + wm + i * 16 + quad * 4;
#pragma unroll
    for (int j = 0; j < 4; ++j) {
      int m = m0 + wnm + j * 16 + l16;
      int b = m >> 12;
      float* yp = y + (b * COUT + crow) * HW + (m & 4095);
#pragma unroll
      for (int r2 = 0; r2 < 4; ++r2)
        yp[r2 * HW] = acc[i][j][r2];
    }
  }
}

// ---------------- K6: BN batch stats (proven) ----------------
__global__ __launch_bounds__(256) void bn_stats_kernel(
    const float* __restrict__ y, float* __restrict__ mean, float* __restrict__ invstd) {
  int c = blockIdx.x;
  int tid = threadIdx.x;
  float s = 0.f, s2 = 0.f;
  for (int b = 0; b < B_; ++b) {
    const float4* p = (const float4*)(y + (b * COUT + c) * HW);
    for (int i = tid; i < HW / 4; i += 256) {
      float4 v = p[i];
      s += v.x + v.y + v.z + v.w;
      s2 = fmaf(v.x, v.x, s2); s2 = fmaf(v.y, v.y, s2);
      s2 = fmaf(v.z, v.z, s2); s2 = fmaf(v.w, v.w, s2);
    }
  }
#pragma unroll
  for (int o = 32; o > 0; o >>= 1) {
    s  += __shfl_down(s, o);
    s2 += __shfl_down(s2, o);
  }
  __shared__ float rs[4], rs2[4];
  int wid = tid >> 6, ln = tid & 63;
  if (ln == 0) { rs[wid] = s; rs2[wid] = s2; }
  __syncthreads();
  if (tid == 0) {
    float S  = rs[0] + rs[1] + rs[2] + rs[3];
    float S2 = rs2[0] + rs2[1] + rs2[2] + rs2[3];
    float m = S / 32768.f;
    float var = S2 / 32768.f - m * m;
    mean[c] = m;
    invstd[c] = rsqrtf(var + 1e-5f);
  }
}

// ---------------- K7: BN apply + SiLU, in place on y (= d_out) (proven) ----------------
__global__ __launch_bounds__(256) void bn_silu_kernel(
    float* __restrict__ y, const float* __restrict__ mean,
    const float* __restrict__ invstd, const float* __restrict__ gamma,
    const float* __restrict__ beta) {
  int i4 = blockIdx.x * 256 + threadIdx.x;   // 2097152 float4s
  int c = (i4 >> 10) & 255;
  float4 v = ((const float4*)y)[i4];
  float m = mean[c], sc = invstd[c] * gamma[c], bt = beta[c];
  float t0 = (v.x - m) * sc + bt;
  float t1 = (v.y - m) * sc + bt;
  float t2 = (v.z - m) * sc + bt;
  float t3 = (v.w - m) * sc + bt;
  float4 o;
  o.x = t0 / (1.f + expf(-t0));
  o.y = t1 / (1.f + expf(-t1));
  o.z = t2 / (1.f + expf(-t2));
  o.w = t3 / (1.f + expf(-t3));
  ((float4*)y)[i4] = o;
}

extern "C" void kernel_launch(void* const* d_in, const int* in_sizes, int n_in,
                              void* d_out, int out_size, void* d_ws, size_t ws_size,
                              hipStream_t stream) {
  const float* x     = (const float*)d_in[0];
  const float* ow    = (const float*)d_in[1];
  const float* ob    = (const float*)d_in[2];
  const float* dw    = (const float*)d_in[3];
  // d_in[4] = dconv bias: cancelled exactly by BN mean-subtraction
  const float* gamma = (const float*)d_in[5];
  const float* beta  = (const float*)d_in[6];
  float* y = (float*)d_out;                  // 8*256*4096 f32 — y buffer, finished in place

  // ws layout (float offsets), total 25,510,400 floats = 102.0 MB (ws = 256 MiB)
  float*  ws   = (float*)d_ws;
  short*  Pb   = (short*)ws;                 // 36*32768*32 shorts = 18874368 floats
  float*  offp = ws + 18874368;              // 8 * 589824 = 4718592
  short4* cidx = (short4*)(ws + 23592960);   // 9*32768 short4 = 589824 floats
  float4* cwt  = (float4*)(ws + 24182784);   // 9*32768 float4 = 1179648 floats
  short*  Wb   = (short*)(ws + 25362432);    // 294912 shorts = 147456 floats
  float*  mean   = ws + 25509888;            // 256
  float*  invstd = ws + 25510144;            // 256

  offset_conv_kernel<<<1024, 256, 0, stream>>>(x, ow, ob, offp);
  wt_cvt_kernel<<<1152, 256, 0, stream>>>(dw, Wb);
  coeff_kernel<<<1152, 256, 0, stream>>>(offp, cidx, cwt);
  sampler_kernel<<<1024, 256, 0, stream>>>(x, cidx, cwt, Pb);
  gemm_kernel<<<512, 256, 0, stream>>>(Wb, Pb, y);
  bn_stats_kernel<<<256, 256, 0, stream>>>(y, mean, invstd);
  bn_silu_kernel<<<8192, 256, 0, stream>>>(y, mean, invstd, gamma, beta);
}

// Round 5
// 258.739 us; speedup vs baseline: 1.2789x; 1.0007x over previous
//
#include <hip/hip_runtime.h>
#include <hip/hip_bf16.h>
#include <math.h>

// (B,Cin,H,W)=(8,128,64,64), Cout=256, K=3, stride=1, pad=1, dil=1
#define B_    8
#define CIN   128
#define Hx    64
#define Wx    64
#define COUT  256
#define HW    4096
#define KTOT  1152      // CIN*9
#define NOFF  18
#define M_    32768     // B*HW
#define OFFSEG (B_ * NOFF * HW)   // 589824 floats per cin-segment partial
#define NCH   36        // K-chunks (chunk = 32 k)

typedef short bf16x8 __attribute__((ext_vector_type(8)));
typedef float f32x4  __attribute__((ext_vector_type(4)));

typedef __attribute__((address_space(1))) const unsigned int gu32;
typedef __attribute__((address_space(3))) unsigned int lu32;
static __device__ __forceinline__ void async_cp16(const short* g, short* l) {
  __builtin_amdgcn_global_load_lds((gu32*)g, (lu32*)l, 16, 0, 0);
}

static __device__ __forceinline__ short f2bf(float f) {
  __hip_bfloat16 h = __float2bfloat16(f);
  return *reinterpret_cast<short*>(&h);
}

// ---------------- K1: offset conv (round-8 proven) ----------------
__global__ __launch_bounds__(256, 4) void offset_conv_kernel(
    const float* __restrict__ x, const float* __restrict__ ow,
    const float* __restrict__ ob, float* __restrict__ offp) {
  __shared__ __align__(16) float lds_w[16 * 9 * 12];   // [ci][ch][12 (9 taps + pad)]
  int blk = blockIdx.x;                     // 0..1023
  int r = blk & 63, seg = (blk >> 6) & 7, chalf = blk >> 9;
  int tid = threadIdx.x;
  for (int i = tid; i < 16 * 9 * 12; i += 256) {
    int t = i % 12;
    int rem = i / 12;                       // ci*9 + ch
    int ch = rem % 9, ci = rem / 9;
    lds_w[i] = (t < 9) ? ow[(chalf * 9 + ch) * KTOT + (seg * 16 + ci) * 9 + t] : 0.f;
  }
  __syncthreads();

  int v = r * 256 + tid;                    // 0..16383
  int wp = v & 31, ho = (v >> 5) & 63, b = v >> 11;
  int wo0 = wp * 2;
  float acc0[9], acc1[9];
#pragma unroll
  for (int c = 0; c < 9; ++c) { acc0[c] = 0.f; acc1[c] = 0.f; }
  const float* xb = x + (b * CIN + seg * 16) * HW;
  for (int ci = 0; ci < 16; ++ci) {
    const float* xp = xb + ci * HW;
    float win[3][4];
#pragma unroll
    for (int ky = 0; ky < 3; ++ky) {
      int iy = ho - 1 + ky;
      bool rok = (iy >= 0) & (iy < Hx);
      const float* rowp = xp + iy * Wx;
#pragma unroll
      for (int c = 0; c < 4; ++c) {
        int ix = wo0 - 1 + c;
        win[ky][c] = (rok & (ix >= 0) & (ix < Wx)) ? rowp[ix] : 0.f;
      }
    }
    const float4* wq = (const float4*)&lds_w[ci * 108];
#pragma unroll
    for (int ch = 0; ch < 9; ++ch) {
      float4 w0 = wq[ch * 3 + 0];
      float4 w1 = wq[ch * 3 + 1];
      float4 w2 = wq[ch * 3 + 2];
      float a0 = acc0[ch], a1 = acc1[ch];
      a0 = fmaf(win[0][0], w0.x, a0); a1 = fmaf(win[0][1], w0.x, a1);
      a0 = fmaf(win[0][1], w0.y, a0); a1 = fmaf(win[0][2], w0.y, a1);
      a0 = fmaf(win[0][2], w0.z, a0); a1 = fmaf(win[0][3], w0.z, a1);
      a0 = fmaf(win[1][0], w0.w, a0); a1 = fmaf(win[1][1], w0.w, a1);
      a0 = fmaf(win[1][1], w1.x, a0); a1 = fmaf(win[1][2], w1.x, a1);
      a0 = fmaf(win[1][2], w1.y, a0); a1 = fmaf(win[1][3], w1.y, a1);
      a0 = fmaf(win[2][0], w1.z, a0); a1 = fmaf(win[2][1], w1.z, a1);
      a0 = fmaf(win[2][1], w1.w, a0); a1 = fmaf(win[2][2], w1.w, a1);
      a0 = fmaf(win[2][2], w2.x, a0); a1 = fmaf(win[2][3], w2.x, a1);
      acc0[ch] = a0; acc1[ch] = a1;
    }
  }
  float* op = offp + seg * OFFSEG + (b * NOFF + chalf * 9) * HW + ho * 64 + wo0;
#pragma unroll
  for (int c = 0; c < 9; ++c) {
    float bias = (seg == 0) ? ob[chalf * 9 + c] : 0.f;
    op[c * HW]     = acc0[c] + bias;
    op[c * HW + 1] = acc1[c] + bias;
  }
}

// ---------------- K2: weight -> bf16 blocked Wb[kc][cout][32] (proven) ----------------
__global__ __launch_bounds__(256) void wt_cvt_kernel(
    const float* __restrict__ w, short* __restrict__ Wb) {
  int t = blockIdx.x * 256 + threadIdx.x;   // 294912
  int ki = t & 31;
  int cout = (t >> 5) & 255;
  int kc = t >> 13;                         // 0..35
  int k = kc * 32 + ki;
  int kk = k >> 7, cin = k & 127;
  Wb[t] = f2bf(w[(cout * CIN + cin) * 9 + kk]);
}

// ---------------- K3: bilinear coefficient tables (proven, 8 partials) ----------------
__global__ __launch_bounds__(256) void coeff_kernel(
    const float* __restrict__ offp, short4* __restrict__ cidx, float4* __restrict__ cwt) {
  int t = blockIdx.x * 256 + threadIdx.x;   // 9*32768
  int m = t & (M_ - 1);
  int kk = t >> 15;                         // 0..8
  int b = m >> 12, ho = (m >> 6) & 63, wo = m & 63;
  int base = (b * NOFF + 2 * kk) * HW + (m & 4095);
  int base2 = base + HW;
  float dy = 0.f, dx = 0.f;
#pragma unroll
  for (int s = 0; s < 8; ++s) {
    dy += offp[base + s * OFFSEG];
    dx += offp[base2 + s * OFFSEG];
  }
  float sy = (float)(ho - 1 + kk / 3) + dy;
  float sx = (float)(wo - 1 + kk % 3) + dx;
  float fy = floorf(sy), fx = floorf(sx);
  int y0 = (int)fy, x0 = (int)fx;
  float wy = sy - fy, wx = sx - fx;
  int y1 = y0 + 1, x1 = x0 + 1;
  int cy0 = min(max(y0, 0), Hx - 1), cy1 = min(max(y1, 0), Hx - 1);
  int cx0 = min(max(x0, 0), Wx - 1), cx1 = min(max(x1, 0), Wx - 1);
  bool vy0 = (y0 >= 0) & (y0 < Hx), vy1 = (y1 >= 0) & (y1 < Hx);
  bool vx0 = (x0 >= 0) & (x0 < Wx), vx1 = (x1 >= 0) & (x1 < Wx);
  short4 id;
  id.x = (short)(cy0 * Wx + cx0); id.y = (short)(cy0 * Wx + cx1);
  id.z = (short)(cy1 * Wx + cx0); id.w = (short)(cy1 * Wx + cx1);
  float4 wv;
  wv.x = (vy0 && vx0) ? (1.f - wy) * (1.f - wx) : 0.f;
  wv.y = (vy0 && vx1) ? (1.f - wy) * wx : 0.f;
  wv.z = (vy1 && vx0) ? wy * (1.f - wx) : 0.f;
  wv.w = (vy1 && vx1) ? wy * wx : 0.f;
  cidx[t] = id;
  cwt[t] = wv;
}

// ---------------- K4: LDS-plane sampler, v5: forced-MLP phase batching ----------------
// Post-mortem v4: removing the launch_bounds cap changed NOTHING (VGPR 52,
// 104us) -> the scheduler CHOOSES the liveness-minimal serial schedule for
// this loop shape; pragmas can't summon v1's deep pipeline. v5 forces MLP
// structurally: 2 half-batches of 8 samples, each with hard phases pinned
// by sched_barrier(0):
//   A: issue all 16 coeff loads (8 short4 + 8 float4)  -> one wait covers all
//   B: issue all 32 ds_read_b64 gathers back-to-back
//   C: 32 FMA + cvt + 8 stores
// Live state ~130 VGPR (8 wv=32, 32 corners=64, 8 id=16 + addr) -> 3 blocks
// /CU = 12 waves/CU, each 8-deep in flight. All array indices are
// compile-time after unroll (no scratch).
// blk = (khalf<<9)|(g2<<3)|b, grid 1024, 32KB LDS. Pb layout unchanged.
__global__ __launch_bounds__(256) void sampler_kernel(
    const float* __restrict__ x, const short4* __restrict__ cidx,
    const float4* __restrict__ cwt, short* __restrict__ Pb) {
  __shared__ __align__(16) float2 ldsp[HW];   // 32768 B: [pixel]{cinA,cinB}
  int blk = blockIdx.x;                     // 0..1023
  int b = blk & 7;
  int g2 = (blk >> 3) & 63;                 // cin-pair 0..63
  int khalf = blk >> 9;
  int cinq = g2 >> 4;                       // cin-quarter (chunk) 0..3
  int e2 = g2 & 15;                         // pair slot within chunk 0..15
  int tid = threadIdx.x;

  // stage 2 planes interleaved: ldsp[pix] = {planeA[pix], planeB[pix]}
  const float2* pl0 = (const float2*)(x + (b * CIN + g2 * 2) * HW);
  const float2* pl1 = (const float2*)(x + (b * CIN + g2 * 2 + 1) * HW);
  float4* q = (float4*)ldsp;
#pragma unroll
  for (int it = 0; it < 8; ++it) {
    int j = it * 256 + tid;                 // float2-pixel-pair index 0..2047
    float2 a = pl0[j];
    float2 c = pl1[j];
    float4 w; w.x = a.x; w.y = c.x; w.z = a.y; w.w = c.y;
    q[j] = w;                               // pixels 2j, 2j+1
  }
  __syncthreads();

  int kk0 = khalf ? 5 : 0;
  int kk1 = khalf ? 9 : 5;
  for (int kk = kk0; kk < kk1; ++kk) {
    int kcg = kk * 4 + cinq;                // 0..35
    const short4* cp = cidx + kk * M_ + b * HW;
    const float4* wp = cwt + kk * M_ + b * HW;
    short* pb = Pb + (kcg * M_ + b * HW) * 32 + e2 * 2;
#pragma unroll
    for (int half = 0; half < 2; ++half) {
      // ---- phase A: issue ALL coeff loads for this half-batch ----
      short4 id[8];
      float4 wv[8];
#pragma unroll
      for (int u = 0; u < 8; ++u) {
        int pos = (half * 8 + u) * 256 + tid;
        id[u] = cp[pos];
        wv[u] = wp[pos];
      }
      __builtin_amdgcn_sched_barrier(0);    // pin: loads issued before gathers
      // ---- phase B: issue ALL LDS gathers back-to-back ----
      float2 va[8], vb[8], vc[8], vd[8];
#pragma unroll
      for (int u = 0; u < 8; ++u) {
        va[u] = ldsp[(int)id[u].x];
        vb[u] = ldsp[(int)id[u].y];
        vc[u] = ldsp[(int)id[u].z];
        vd[u] = ldsp[(int)id[u].w];
      }
      __builtin_amdgcn_sched_barrier(0);    // pin: gathers issued before compute
      // ---- phase C: FMA + cvt + store ----
#pragma unroll
      for (int u = 0; u < 8; ++u) {
        int pos = (half * 8 + u) * 256 + tid;
        float s0 = wv[u].x * va[u].x + wv[u].y * vb[u].x
                 + wv[u].z * vc[u].x + wv[u].w * vd[u].x;
        float s1 = wv[u].x * va[u].y + wv[u].y * vb[u].y
                 + wv[u].z * vc[u].y + wv[u].w * vd[u].y;
        union { short s[2]; int v; } bu;
        bu.s[0] = f2bf(s0);
        bu.s[1] = f2bf(s1);
        *(int*)&pb[pos * 32] = bu.v;
      }
    }
  }
}

// ---------------- K5: single bf16 MFMA GEMM, m97-style async K-loop ----------------
// blk: mt = blk&255, ct = blk>>8 (ct-pair shares XCD -> Pb L2 reuse).
// Tile 128 cout x 128 m, K=1152 in 36 chunks of 32. Double-buffered 16KB LDS
// tiles staged by global_load_lds (flat 8KB A + 8KB B copies); ONE barrier per
// chunk; next chunk's DMA flies across the 16 MFMAs.
__global__ __launch_bounds__(256, 2) void gemm_kernel(
    const short* __restrict__ Wb, const short* __restrict__ Pb,
    float* __restrict__ y) {
  __shared__ __align__(16) short lds[2][8192];   // [buf][ A 4096 | B 4096 ] shorts

  int tid = threadIdx.x;
  int mt = blockIdx.x & 255;
  int ct = blockIdx.x >> 8;
  int cout0 = ct * 128;
  int m0 = mt * 128;

  int lane = tid & 63, wave = tid >> 6;
  int quad = lane >> 4, l16 = lane & 15;
  int wm = (wave & 1) << 6;          // cout sub-tile 0/64
  int wnm = (wave >> 1) << 6;        // m sub-tile 0/64

  // staging roles: waves 0,1 -> A halves; waves 2,3 -> B halves
  int isB = wave >> 1;
  int sub = wave & 1;
  const short* srcbase = isB ? (Pb + m0 * 32) : (Wb + cout0 * 32);
  const int sstride = isB ? (M_ * 32) : (256 * 32);
  const int soff = sub * 2048 + lane * 8;        // shorts
  const int doff = isB * 4096 + sub * 2048 + lane * 8;

  f32x4 zero = {0.f, 0.f, 0.f, 0.f};
  f32x4 acc[4][4];
#pragma unroll
  for (int i = 0; i < 4; ++i)
#pragma unroll
    for (int j = 0; j < 4; ++j) acc[i][j] = zero;

  // prologue: chunk 0 -> buf 0
  {
    const short* s = srcbase + soff;
    short* d = &lds[0][doff];
#pragma unroll
    for (int j = 0; j < 4; ++j)
      async_cp16(s + j * 512, d + j * 512);
  }

  for (int ch = 0; ch < NCH; ++ch) {
    int p = ch & 1;
    __syncthreads();                 // drains DMA -> buf p ready; frag reads of p^1 done
    if (ch < NCH - 1) {
      const short* s = srcbase + (ch + 1) * sstride + soff;
      short* d = &lds[p ^ 1][doff];
#pragma unroll
      for (int j = 0; j < 4; ++j)
        async_cp16(s + j * 512, d + j * 512);   // flies across the MFMAs below
    }
    const short* sa = &lds[p][0];
    const short* sb = &lds[p][4096];
    bf16x8 af[4], bfr[4];
#pragma unroll
    for (int i = 0; i < 4; ++i)
      af[i] = *(const bf16x8*)&sa[(wm + i * 16 + l16) * 32 + quad * 8];
#pragma unroll
    for (int j = 0; j < 4; ++j)
      bfr[j] = *(const bf16x8*)&sb[(wnm + j * 16 + l16) * 32 + quad * 8];
#pragma unroll
    for (int i = 0; i < 4; ++i)
#pragma unroll
      for (int j = 0; j < 4; ++j)
        acc[i][j] = __builtin_amdgcn_mfma_f32_16x16x32_bf16(af[i], bfr[j], acc[i][j], 0, 0, 0);
  }

  // epilogue: write y once (dconv bias cancels in BN mean-subtraction)
#pragma unroll
  for (int i = 0; i < 4; ++i) {
    int crow = cout0 + wm + i * 16 + quad * 4;
#pragma unroll
    for (int j = 0; j < 4; ++j) {
      int m = m0 + wnm + j * 16 + l16;
      int b = m >> 12;
      float* yp = y + (b * COUT + crow) * HW + (m & 4095);
#pragma unroll
      for (int r2 = 0; r2 < 4; ++r2)
        yp[r2 * HW] = acc[i][j][r2];
    }
  }
}

// ---------------- K6: BN batch stats (proven) ----------------
__global__ __launch_bounds__(256) void bn_stats_kernel(
    const float* __restrict__ y, float* __restrict__ mean, float* __restrict__ invstd) {
  int c = blockIdx.x;
  int tid = threadIdx.x;
  float s = 0.f, s2 = 0.f;
  for (int b = 0; b < B_; ++b) {
    const float4* p = (const float4*)(y + (b * COUT + c) * HW);
    for (int i = tid; i < HW / 4; i += 256) {
      float4 v = p[i];
      s += v.x + v.y + v.z + v.w;
      s2 = fmaf(v.x, v.x, s2); s2 = fmaf(v.y, v.y, s2);
      s2 = fmaf(v.z, v.z, s2); s2 = fmaf(v.w, v.w, s2);
    }
  }
#pragma unroll
  for (int o = 32; o > 0; o >>= 1) {
    s  += __shfl_down(s, o);
    s2 += __shfl_down(s2, o);
  }
  __shared__ float rs[4], rs2[4];
  int wid = tid >> 6, ln = tid & 63;
  if (ln == 0) { rs[wid] = s; rs2[wid] = s2; }
  __syncthreads();
  if (tid == 0) {
    float S  = rs[0] + rs[1] + rs[2] + rs[3];
    float S2 = rs2[0] + rs2[1] + rs2[2] + rs2[3];
    float m = S / 32768.f;
    float var = S2 / 32768.f - m * m;
    mean[c] = m;
    invstd[c] = rsqrtf(var + 1e-5f);
  }
}

// ---------------- K7: BN apply + SiLU, in place on y (= d_out) (proven) ----------------
__global__ __launch_bounds__(256) void bn_silu_kernel(
    float* __restrict__ y, const float* __restrict__ mean,
    const float* __restrict__ invstd, const float* __restrict__ gamma,
    const float* __restrict__ beta) {
  int i4 = blockIdx.x * 256 + threadIdx.x;   // 2097152 float4s
  int c = (i4 >> 10) & 255;
  float4 v = ((const float4*)y)[i4];
  float m = mean[c], sc = invstd[c] * gamma[c], bt = beta[c];
  float t0 = (v.x - m) * sc + bt;
  float t1 = (v.y - m) * sc + bt;
  float t2 = (v.z - m) * sc + bt;
  float t3 = (v.w - m) * sc + bt;
  float4 o;
  o.x = t0 / (1.f + expf(-t0));
  o.y = t1 / (1.f + expf(-t1));
  o.z = t2 / (1.f + expf(-t2));
  o.w = t3 / (1.f + expf(-t3));
  ((float4*)y)[i4] = o;
}

extern "C" void kernel_launch(void* const* d_in, const int* in_sizes, int n_in,
                              void* d_out, int out_size, void* d_ws, size_t ws_size,
                              hipStream_t stream) {
  const float* x     = (const float*)d_in[0];
  const float* ow    = (const float*)d_in[1];
  const float* ob    = (const float*)d_in[2];
  const float* dw    = (const float*)d_in[3];
  // d_in[4] = dconv bias: cancelled exactly by BN mean-subtraction
  const float* gamma = (const float*)d_in[5];
  const float* beta  = (const float*)d_in[6];
  float* y = (float*)d_out;                  // 8*256*4096 f32 — y buffer, finished in place

  // ws layout (float offsets), total 25,510,400 floats = 102.0 MB (ws = 256 MiB)
  float*  ws   = (float*)d_ws;
  short*  Pb   = (short*)ws;                 // 36*32768*32 shorts = 18874368 floats
  float*  offp = ws + 18874368;              // 8 * 589824 = 4718592
  short4* cidx = (short4*)(ws + 23592960);   // 9*32768 short4 = 589824 floats
  float4* cwt  = (float4*)(ws + 24182784);   // 9*32768 float4 = 1179648 floats
  short*  Wb   = (short*)(ws + 25362432);    // 294912 shorts = 147456 floats
  float*  mean   = ws + 25509888;            // 256
  float*  invstd = ws + 25510144;            // 256

  offset_conv_kernel<<<1024, 256, 0, stream>>>(x, ow, ob, offp);
  wt_cvt_kernel<<<1152, 256, 0, stream>>>(dw, Wb);
  coeff_kernel<<<1152, 256, 0, stream>>>(offp, cidx, cwt);
  sampler_kernel<<<1024, 256, 0, stream>>>(x, cidx, cwt, Pb);
  gemm_kernel<<<512, 256, 0, stream>>>(Wb, Pb, y);
  bn_stats_kernel<<<256, 256, 0, stream>>>(y, mean, invstd);
  bn_silu_kernel<<<8192, 256, 0, stream>>>(y, mean, invstd, gamma, beta);
}

// Round 6
// 211.820 us; speedup vs baseline: 1.5621x; 1.2215x over previous
//
#include <hip/hip_runtime.h>
#include <hip/hip_bf16.h>
#include <math.h>

// (B,Cin,H,W)=(8,128,64,64), Cout=256, K=3, stride=1, pad=1, dil=1
#define B_    8
#define CIN   128
#define Hx    64
#define Wx    64
#define COUT  256
#define HW    4096
#define KTOT  1152      // CIN*9
#define NOFF  18
#define M_    32768     // B*HW
#define OFFSEG (B_ * NOFF * HW)   // 589824 floats per cin-segment partial
#define NCH   36        // K-chunks (chunk = 32 k)

typedef short bf16x8 __attribute__((ext_vector_type(8)));
typedef float f32x4  __attribute__((ext_vector_type(4)));

typedef __attribute__((address_space(1))) const unsigned int gu32;
typedef __attribute__((address_space(3))) unsigned int lu32;
static __device__ __forceinline__ void async_cp16(const short* g, short* l) {
  __builtin_amdgcn_global_load_lds((gu32*)g, (lu32*)l, 16, 0, 0);
}

static __device__ __forceinline__ short f2bf(float f) {
  __hip_bfloat16 h = __float2bfloat16(f);
  return *reinterpret_cast<short*>(&h);
}

static __device__ __forceinline__ float b2f(unsigned short u) {
  unsigned int v = ((unsigned int)u) << 16;
  return __uint_as_float(v);
}

// ---------------- K1: offset conv (round-8 proven) ----------------
__global__ __launch_bounds__(256, 4) void offset_conv_kernel(
    const float* __restrict__ x, const float* __restrict__ ow,
    const float* __restrict__ ob, float* __restrict__ offp) {
  __shared__ __align__(16) float lds_w[16 * 9 * 12];   // [ci][ch][12 (9 taps + pad)]
  int blk = blockIdx.x;                     // 0..1023
  int r = blk & 63, seg = (blk >> 6) & 7, chalf = blk >> 9;
  int tid = threadIdx.x;
  for (int i = tid; i < 16 * 9 * 12; i += 256) {
    int t = i % 12;
    int rem = i / 12;                       // ci*9 + ch
    int ch = rem % 9, ci = rem / 9;
    lds_w[i] = (t < 9) ? ow[(chalf * 9 + ch) * KTOT + (seg * 16 + ci) * 9 + t] : 0.f;
  }
  __syncthreads();

  int v = r * 256 + tid;                    // 0..16383
  int wp = v & 31, ho = (v >> 5) & 63, b = v >> 11;
  int wo0 = wp * 2;
  float acc0[9], acc1[9];
#pragma unroll
  for (int c = 0; c < 9; ++c) { acc0[c] = 0.f; acc1[c] = 0.f; }
  const float* xb = x + (b * CIN + seg * 16) * HW;
  for (int ci = 0; ci < 16; ++ci) {
    const float* xp = xb + ci * HW;
    float win[3][4];
#pragma unroll
    for (int ky = 0; ky < 3; ++ky) {
      int iy = ho - 1 + ky;
      bool rok = (iy >= 0) & (iy < Hx);
      const float* rowp = xp + iy * Wx;
#pragma unroll
      for (int c = 0; c < 4; ++c) {
        int ix = wo0 - 1 + c;
        win[ky][c] = (rok & (ix >= 0) & (ix < Wx)) ? rowp[ix] : 0.f;
      }
    }
    const float4* wq = (const float4*)&lds_w[ci * 108];
#pragma unroll
    for (int ch = 0; ch < 9; ++ch) {
      float4 w0 = wq[ch * 3 + 0];
      float4 w1 = wq[ch * 3 + 1];
      float4 w2 = wq[ch * 3 + 2];
      float a0 = acc0[ch], a1 = acc1[ch];
      a0 = fmaf(win[0][0], w0.x, a0); a1 = fmaf(win[0][1], w0.x, a1);
      a0 = fmaf(win[0][1], w0.y, a0); a1 = fmaf(win[0][2], w0.y, a1);
      a0 = fmaf(win[0][2], w0.z, a0); a1 = fmaf(win[0][3], w0.z, a1);
      a0 = fmaf(win[1][0], w0.w, a0); a1 = fmaf(win[1][1], w0.w, a1);
      a0 = fmaf(win[1][1], w1.x, a0); a1 = fmaf(win[1][2], w1.x, a1);
      a0 = fmaf(win[1][2], w1.y, a0); a1 = fmaf(win[1][3], w1.y, a1);
      a0 = fmaf(win[2][0], w1.z, a0); a1 = fmaf(win[2][1], w1.z, a1);
      a0 = fmaf(win[2][1], w1.w, a0); a1 = fmaf(win[2][2], w1.w, a1);
      a0 = fmaf(win[2][2], w2.x, a0); a1 = fmaf(win[2][3], w2.x, a1);
      acc0[ch] = a0; acc1[ch] = a1;
    }
  }
  float* op = offp + seg * OFFSEG + (b * NOFF + chalf * 9) * HW + ho * 64 + wo0;
#pragma unroll
  for (int c = 0; c < 9; ++c) {
    float bias = (seg == 0) ? ob[chalf * 9 + c] : 0.f;
    op[c * HW]     = acc0[c] + bias;
    op[c * HW + 1] = acc1[c] + bias;
  }
}

// ---------------- K2: weight -> bf16 blocked Wb[kc][cout][32] (proven) ----------------
__global__ __launch_bounds__(256) void wt_cvt_kernel(
    const float* __restrict__ w, short* __restrict__ Wb) {
  int t = blockIdx.x * 256 + threadIdx.x;   // 294912
  int ki = t & 31;
  int cout = (t >> 5) & 255;
  int kc = t >> 13;                         // 0..35
  int k = kc * 32 + ki;
  int kk = k >> 7, cin = k & 127;
  Wb[t] = f2bf(w[(cout * CIN + cin) * 9 + kk]);
}

// ---------------- K3: bilinear coefficient tables (proven, 8 partials) ----------------
__global__ __launch_bounds__(256) void coeff_kernel(
    const float* __restrict__ offp, short4* __restrict__ cidx, float4* __restrict__ cwt) {
  int t = blockIdx.x * 256 + threadIdx.x;   // 9*32768
  int m = t & (M_ - 1);
  int kk = t >> 15;                         // 0..8
  int b = m >> 12, ho = (m >> 6) & 63, wo = m & 63;
  int base = (b * NOFF + 2 * kk) * HW + (m & 4095);
  int base2 = base + HW;
  float dy = 0.f, dx = 0.f;
#pragma unroll
  for (int s = 0; s < 8; ++s) {
    dy += offp[base + s * OFFSEG];
    dx += offp[base2 + s * OFFSEG];
  }
  float sy = (float)(ho - 1 + kk / 3) + dy;
  float sx = (float)(wo - 1 + kk % 3) + dx;
  float fy = floorf(sy), fx = floorf(sx);
  int y0 = (int)fy, x0 = (int)fx;
  float wy = sy - fy, wx = sx - fx;
  int y1 = y0 + 1, x1 = x0 + 1;
  int cy0 = min(max(y0, 0), Hx - 1), cy1 = min(max(y1, 0), Hx - 1);
  int cx0 = min(max(x0, 0), Wx - 1), cx1 = min(max(x1, 0), Wx - 1);
  bool vy0 = (y0 >= 0) & (y0 < Hx), vy1 = (y1 >= 0) & (y1 < Hx);
  bool vx0 = (x0 >= 0) & (x0 < Wx), vx1 = (x1 >= 0) & (x1 < Wx);
  short4 id;
  id.x = (short)(cy0 * Wx + cx0); id.y = (short)(cy0 * Wx + cx1);
  id.z = (short)(cy1 * Wx + cx0); id.w = (short)(cy1 * Wx + cx1);
  float4 wv;
  wv.x = (vy0 && vx0) ? (1.f - wy) * (1.f - wx) : 0.f;
  wv.y = (vy0 && vx1) ? (1.f - wy) * wx : 0.f;
  wv.z = (vy1 && vx0) ? wy * (1.f - wx) : 0.f;
  wv.w = (vy1 && vx1) ? wy * wx : 0.f;
  cidx[t] = id;
  cwt[t] = wv;
}

// ---------------- K4: sampler v6 — bf16 4-cin planes in 32KB ----------------
// Post-mortem v2-v5: ALL 2-cin variants land at ~104us regardless of
// occupancy/VGPR/sched_barrier; v1's 4-cin structure = 78us. The controlling
// variable is latency-EVENT count per unit work (coeff loads + gathers +
// stores per cin), not waves or codegen. v6 maximizes amortization at
// minimal LDS:
//  * 4 planes staged as bf16 {c0,c1,c2,c3} per pixel = 8B/px = 32KB LDS.
//  * ONE ds_read_b64 per bilinear corner serves ALL 4 cins (v1: 16 b32).
//  * one coeff-load pair per 4 cins -> 9.4M iters (half of v3-v5).
//  * 8B int2 stores, v1's exact Pb slot layout (e*4 shorts).
//  * 32KB -> 4 blocks/CU; grid 1024 via 4-way kk split {0-2},{3-4},{5-6},{7-8}.
// Precision note: x rounds to bf16 BEFORE interpolation (one extra 2^-9
// relative error source on patches, which are bf16 anyway). Expect absmax
// 0.03125 -> <=0.0625. Fallback if tolerance fails: f32 planes, row-split tile.
// blk = (kq<<8)|(g4<<3)|b, grid 1024.
__global__ __launch_bounds__(256) void sampler_kernel(
    const float* __restrict__ x, const short4* __restrict__ cidx,
    const float4* __restrict__ cwt, short* __restrict__ Pb) {
  __shared__ __align__(16) ushort4 ldsp[HW];   // 32768 B: [pixel]{4 bf16 cins}
  int blk = blockIdx.x;                     // 0..1023
  int b = blk & 7;
  int g4 = (blk >> 3) & 31;                 // cin-quad 0..31
  int kq = blk >> 8;                        // 0..3
  int cinq = g4 >> 3;                       // chunk quarter 0..3
  int e = g4 & 7;                           // quad slot within chunk (8 quads)
  int tid = threadIdx.x;

  // stage 4 planes -> bf16 interleaved. Coalesced f32 reads, 8B LDS writes.
  const float* p0 = x + (b * CIN + g4 * 4) * HW;
  const float* p1 = p0 + HW;
  const float* p2 = p0 + 2 * HW;
  const float* p3 = p0 + 3 * HW;
#pragma unroll
  for (int it = 0; it < 16; ++it) {
    int p = it * 256 + tid;
    ushort4 pk;
    pk.x = (unsigned short)f2bf(p0[p]);
    pk.y = (unsigned short)f2bf(p1[p]);
    pk.z = (unsigned short)f2bf(p2[p]);
    pk.w = (unsigned short)f2bf(p3[p]);
    ldsp[p] = pk;
  }
  __syncthreads();

  int kk0 = (kq == 0) ? 0 : (kq * 2 + 1);   // {0,3,5,7}
  int kk1 = kk0 + ((kq == 0) ? 3 : 2);      // {3,5,7,9}
  for (int kk = kk0; kk < kk1; ++kk) {
    int kcg = kk * 4 + cinq;                // 0..35
    const short4* cp = cidx + kk * M_ + b * HW;
    const float4* wp = cwt + kk * M_ + b * HW;
    short* pb = Pb + (kcg * M_ + b * HW) * 32 + e * 4;
#pragma unroll
    for (int it = 0; it < 16; ++it) {
      int pos = it * 256 + tid;
      short4 id = cp[pos];
      float4 wv = wp[pos];
      ushort4 A = ldsp[(int)id.x];
      ushort4 Bv = ldsp[(int)id.y];
      ushort4 C = ldsp[(int)id.z];
      ushort4 D = ldsp[(int)id.w];
      float s0 = wv.x * b2f(A.x) + wv.y * b2f(Bv.x) + wv.z * b2f(C.x) + wv.w * b2f(D.x);
      float s1 = wv.x * b2f(A.y) + wv.y * b2f(Bv.y) + wv.z * b2f(C.y) + wv.w * b2f(D.y);
      float s2 = wv.x * b2f(A.z) + wv.y * b2f(Bv.z) + wv.z * b2f(C.z) + wv.w * b2f(D.z);
      float s3 = wv.x * b2f(A.w) + wv.y * b2f(Bv.w) + wv.z * b2f(C.w) + wv.w * b2f(D.w);
      union { short s[4]; int2 v; } bu;
      bu.s[0] = f2bf(s0);
      bu.s[1] = f2bf(s1);
      bu.s[2] = f2bf(s2);
      bu.s[3] = f2bf(s3);
      *(int2*)&pb[pos * 32] = bu.v;
    }
  }
}

// ---------------- K5: single bf16 MFMA GEMM, m97-style async K-loop ----------------
// blk: mt = blk&255, ct = blk>>8 (ct-pair shares XCD -> Pb L2 reuse).
// Tile 128 cout x 128 m, K=1152 in 36 chunks of 32. Double-buffered 16KB LDS
// tiles staged by global_load_lds (flat 8KB A + 8KB B copies); ONE barrier per
// chunk; next chunk's DMA flies across the 16 MFMAs.
__global__ __launch_bounds__(256, 2) void gemm_kernel(
    const short* __restrict__ Wb, const short* __restrict__ Pb,
    float* __restrict__ y) {
  __shared__ __align__(16) short lds[2][8192];   // [buf][ A 4096 | B 4096 ] shorts

  int tid = threadIdx.x;
  int mt = blockIdx.x & 255;
  int ct = blockIdx.x >> 8;
  int cout0 = ct * 128;
  int m0 = mt * 128;

  int lane = tid & 63, wave = tid >> 6;
  int quad = lane >> 4, l16 = lane & 15;
  int wm = (wave & 1) << 6;          // cout sub-tile 0/64
  int wnm = (wave >> 1) << 6;        // m sub-tile 0/64

  // staging roles: waves 0,1 -> A halves; waves 2,3 -> B halves
  int isB = wave >> 1;
  int sub = wave & 1;
  const short* srcbase = isB ? (Pb + m0 * 32) : (Wb + cout0 * 32);
  const int sstride = isB ? (M_ * 32) : (256 * 32);
  const int soff = sub * 2048 + lane * 8;        // shorts
  const int doff = isB * 4096 + sub * 2048 + lane * 8;

  f32x4 zero = {0.f, 0.f, 0.f, 0.f};
  f32x4 acc[4][4];
#pragma unroll
  for (int i = 0; i < 4; ++i)
#pragma unroll
    for (int j = 0; j < 4; ++j) acc[i][j] = zero;

  // prologue: chunk 0 -> buf 0
  {
    const short* s = srcbase + soff;
    short* d = &lds[0][doff];
#pragma unroll
    for (int j = 0; j < 4; ++j)
      async_cp16(s + j * 512, d + j * 512);
  }

  for (int ch = 0; ch < NCH; ++ch) {
    int p = ch & 1;
    __syncthreads();                 // drains DMA -> buf p ready; frag reads of p^1 done
    if (ch < NCH - 1) {
      const short* s = srcbase + (ch + 1) * sstride + soff;
      short* d = &lds[p ^ 1][doff];
#pragma unroll
      for (int j = 0; j < 4; ++j)
        async_cp16(s + j * 512, d + j * 512);   // flies across the MFMAs below
    }
    const short* sa = &lds[p][0];
    const short* sb = &lds[p][4096];
    bf16x8 af[4], bfr[4];
#pragma unroll
    for (int i = 0; i < 4; ++i)
      af[i] = *(const bf16x8*)&sa[(wm + i * 16 + l16) * 32 + quad * 8];
#pragma unroll
    for (int j = 0; j < 4; ++j)
      bfr[j] = *(const bf16x8*)&sb[(wnm + j * 16 + l16) * 32 + quad * 8];
#pragma unroll
    for (int i = 0; i < 4; ++i)
#pragma unroll
      for (int j = 0; j < 4; ++j)
        acc[i][j] = __builtin_amdgcn_mfma_f32_16x16x32_bf16(af[i], bfr[j], acc[i][j], 0, 0, 0);
  }

  // epilogue: write y once (dconv bias cancels in BN mean-subtraction)
#pragma unroll
  for (int i = 0; i < 4; ++i) {
    int crow = cout0 + wm + i * 16 + quad * 4;
#pragma unroll
    for (int j = 0; j < 4; ++j) {
      int m = m0 + wnm + j * 16 + l16;
      int b = m >> 12;
      float* yp = y + (b * COUT + crow) * HW + (m & 4095);
#pragma unroll
      for (int r2 = 0; r2 < 4; ++r2)
        yp[r2 * HW] = acc[i][j][r2];
    }
  }
}

// ---------------- K6: BN batch stats (proven) ----------------
__global__ __launch_bounds__(256) void bn_stats_kernel(
    const float* __restrict__ y, float* __restrict__ mean, float* __restrict__ invstd) {
  int c = blockIdx.x;
  int tid = threadIdx.x;
  float s = 0.f, s2 = 0.f;
  for (int b = 0; b < B_; ++b) {
    const float4* p = (const float4*)(y + (b * COUT + c) * HW);
    for (int i = tid; i < HW / 4; i += 256) {
      float4 v = p[i];
      s += v.x + v.y + v.z + v.w;
      s2 = fmaf(v.x, v.x, s2); s2 = fmaf(v.y, v.y, s2);
      s2 = fmaf(v.z, v.z, s2); s2 = fmaf(v.w, v.w, s2);
    }
  }
#pragma unroll
  for (int o = 32; o > 0; o >>= 1) {
    s  += __shfl_down(s, o);
    s2 += __shfl_down(s2, o);
  }
  __shared__ float rs[4], rs2[4];
  int wid = tid >> 6, ln = tid & 63;
  if (ln == 0) { rs[wid] = s; rs2[wid] = s2; }
  __syncthreads();
  if (tid == 0) {
    float S  = rs[0] + rs[1] + rs[2] + rs[3];
    float S2 = rs2[0] + rs2[1] + rs2[2] + rs2[3];
    float m = S / 32768.f;
    float var = S2 / 32768.f - m * m;
    mean[c] = m;
    invstd[c] = rsqrtf(var + 1e-5f);
  }
}

// ---------------- K7: BN apply + SiLU, in place on y (= d_out) (proven) ----------------
__global__ __launch_bounds__(256) void bn_silu_kernel(
    float* __restrict__ y, const float* __restrict__ mean,
    const float* __restrict__ invstd, const float* __restrict__ gamma,
    const float* __restrict__ beta) {
  int i4 = blockIdx.x * 256 + threadIdx.x;   // 2097152 float4s
  int c = (i4 >> 10) & 255;
  float4 v = ((const float4*)y)[i4];
  float m = mean[c], sc = invstd[c] * gamma[c], bt = beta[c];
  float t0 = (v.x - m) * sc + bt;
  float t1 = (v.y - m) * sc + bt;
  float t2 = (v.z - m) * sc + bt;
  float t3 = (v.w - m) * sc + bt;
  float4 o;
  o.x = t0 / (1.f + expf(-t0));
  o.y = t1 / (1.f + expf(-t1));
  o.z = t2 / (1.f + expf(-t2));
  o.w = t3 / (1.f + expf(-t3));
  ((float4*)y)[i4] = o;
}

extern "C" void kernel_launch(void* const* d_in, const int* in_sizes, int n_in,
                              void* d_out, int out_size, void* d_ws, size_t ws_size,
                              hipStream_t stream) {
  const float* x     = (const float*)d_in[0];
  const float* ow    = (const float*)d_in[1];
  const float* ob    = (const float*)d_in[2];
  const float* dw    = (const float*)d_in[3];
  // d_in[4] = dconv bias: cancelled exactly by BN mean-subtraction
  const float* gamma = (const float*)d_in[5];
  const float* beta  = (const float*)d_in[6];
  float* y = (float*)d_out;                  // 8*256*4096 f32 — y buffer, finished in place

  // ws layout (float offsets), total 25,510,400 floats = 102.0 MB (ws = 256 MiB)
  float*  ws   = (float*)d_ws;
  short*  Pb   = (short*)ws;                 // 36*32768*32 shorts = 18874368 floats
  float*  offp = ws + 18874368;              // 8 * 589824 = 4718592
  short4* cidx = (short4*)(ws + 23592960);   // 9*32768 short4 = 589824 floats
  float4* cwt  = (float4*)(ws + 24182784);   // 9*32768 float4 = 1179648 floats
  short*  Wb   = (short*)(ws + 25362432);    // 294912 shorts = 147456 floats
  float*  mean   = ws + 25509888;            // 256
  float*  invstd = ws + 25510144;            // 256

  offset_conv_kernel<<<1024, 256, 0, stream>>>(x, ow, ob, offp);
  wt_cvt_kernel<<<1152, 256, 0, stream>>>(dw, Wb);
  coeff_kernel<<<1152, 256, 0, stream>>>(offp, cidx, cwt);
  sampler_kernel<<<1024, 256, 0, stream>>>(x, cidx, cwt, Pb);
  gemm_kernel<<<512, 256, 0, stream>>>(Wb, Pb, y);
  bn_stats_kernel<<<256, 256, 0, stream>>>(y, mean, invstd);
  bn_silu_kernel<<<8192, 256, 0, stream>>>(y, mean, invstd, gamma, beta);
}